// Round 7
// baseline (407.389 us; speedup 1.0000x reference)
//
#include <hip/hip_runtime.h>
#include <cmath>

#define A_TOT 76725
#define A_PAD 76728   // multiple of 4
#define NBATCH 8
#define NCLS 80
#define NANCH 9
#define NOUT 200

#define MCAP 1024     // compacted-candidate capacity (power of two, bitonic)
#define NTH 1024
#define NBUCK 4096
#define CHUNK 64
#define NSLC 32       // parallel slices per batch for compact
#define KBASE 0x3EC00000u   // f32 bits of 0.375 — below any passing key (>=~0.40547)
#define KSHIFT 16
#define NCHUNKS 36    // 25 (lvl0) + 7 (lvl1) + 2 (lvl2) + 1 (lvl3) + 1 (lvl4)

// ---------------------------------------------------------------------------
// f64 box decode, identical expressions to the verified rounds (absmax 0.0)
// — do not reorder these ops. Used by compact (hot, <=1024/batch) and by the
// greedy fallback (pathological only).
// ---------------------------------------------------------------------------
__device__ __forceinline__ void decode_box(int b, int j,
                                           const float* __restrict__ rg0,
                                           const float* __restrict__ rg1,
                                           const float* __restrict__ rg2,
                                           const float* __restrict__ rg3,
                                           const float* __restrict__ rg4,
                                           const float* __restrict__ anchors,
                                           double* __restrict__ o4)
{
    int s, base;
    const float* rg;
    if (j >= 76500)      { s = 25;   base = 76500; rg = rg4; }
    else if (j >= 75600) { s = 100;  base = 75600; rg = rg3; }
    else if (j >= 72000) { s = 400;  base = 72000; rg = rg2; }
    else if (j >= 57600) { s = 1600; base = 57600; rg = rg1; }
    else                 { s = 6400; base = 0;     rg = rg0; }
    const int rem = j - base;
    const int loc = rem / 9;
    const int aa  = rem - loc * 9;
    const size_t ro = ((size_t)(b * NANCH + aa) * 4) * s + loc;
    const float f0 = rg[ro];
    const float f1 = rg[ro + (size_t)s];
    const float f2 = rg[ro + 2 * (size_t)s];
    const float f3 = rg[ro + 3 * (size_t)s];

    double d0 = (double)f0, d1 = (double)f1, d2 = (double)f2, d3 = (double)f3;
    const float4 av = *(const float4*)(anchors + (size_t)j * 4);
    double ax1 = (double)av.x, ay1 = (double)av.y;
    double ax2 = (double)av.z, ay2 = (double)av.w;
    double aw = ax2 - ax1, ah = ay2 - ay1;
    double acx = ax1 + 0.5 * aw, acy = ay1 + 0.5 * ah;
    double cx = acx + d0 * aw, cy = acy + d1 * ah;
    double w = aw * exp(d2), h = ah * exp(d3);
    o4[0] = cx - 0.5 * w;
    o4[1] = cy - 0.5 * h;
    o4[2] = cx + 0.5 * w;
    o4[3] = cy + 0.5 * h;
}

// ---------------------------------------------------------------------------
// prep: grid (36 chunks-of-256-locations, 9 anchors, 8 batch) x 512 threads.
// __launch_bounds__(512, 4): min 4 waves/EU relaxes the compiler's VGPR
// target from 64 to ~128 so the TEN independent float4 loads below can all
// be hoisted ahead of the compare chain (MLP ~10/wave). Class dim split
// across EIGHT 64-thread slices (10 classes each), merged via LDS in
// ascending slice order with strict-> (first-max-index preserved).
// Emits key = f32 logit bits (0 if below threshold) + cat, fuses the
// per-batch bucket histogram via LDS atomics.
// Threshold: exact band filter — sigma(0.405)=0.599889<0.6,
// sigma(0.406)=0.600128>=0.6, f64-eval error ~1e-16 << margin, so only
// mv in (0.405,0.406) evaluates the verbatim f64 predicate.
// Ordering by f32-logit-bits == ordering by f64 sigmoid (strict monotone).
// ---------------------------------------------------------------------------
#define CMP4(vv, cc)                                            \
    do {                                                        \
        if ((vv).x > m.x) { m.x = (vv).x; mcx = (cc); }         \
        if ((vv).y > m.y) { m.y = (vv).y; mcy = (cc); }         \
        if ((vv).z > m.z) { m.z = (vv).z; mcz = (cc); }         \
        if ((vv).w > m.w) { m.w = (vv).w; mcw = (cc); }         \
    } while (0)

__global__ __launch_bounds__(512, 4)
void prep_kernel(const float* __restrict__ lg0, const float* __restrict__ lg1,
                 const float* __restrict__ lg2, const float* __restrict__ lg3,
                 const float* __restrict__ lg4,
                 unsigned* __restrict__ keys,
                 unsigned char* __restrict__ cats,
                 unsigned* __restrict__ hist)
{
    const int cx = blockIdx.x;
    const int a  = blockIdx.y;
    const int b  = blockIdx.z;
    int lvl, local;
    if (cx < 25)      { lvl = 0; local = cx; }
    else if (cx < 32) { lvl = 1; local = cx - 25; }
    else if (cx < 34) { lvl = 2; local = cx - 32; }
    else if (cx < 35) { lvl = 3; local = 0; }
    else              { lvl = 4; local = 0; }

    const int   sarr[5] = {6400, 1600, 400, 100, 25};
    const int   barr[5] = {0, 57600, 72000, 75600, 76500};
    const float* lgs[5] = {lg0, lg1, lg2, lg3, lg4};
    const int s = sarr[lvl], base = barr[lvl];
    const float* lg = lgs[lvl];

    __shared__ unsigned lh[NBUCK];       // 16 KB
    __shared__ float4   smv[7][64];      // 7 KB
    __shared__ int      smc[7][64][4];   // 7 KB

    const int tid = threadIdx.x;
    for (int i = tid; i < NBUCK; i += 512) lh[i] = 0u;

    const int t2 = tid & 63;            // 64 location-groups x 4 locs = 256 locs
    const int q  = tid >> 6;            // class slice 0..7 (10 classes each)
    const int c0 = q * 10;
    const int locbase = local * 256 + t2 * 4;
    const bool act = locbase < s;

    float mj[4]  = {-1e30f, -1e30f, -1e30f, -1e30f};
    int   mcj[4] = {0, 0, 0, 0};

    if (act) {
        const float* lga = lg + ((size_t)(b * NANCH + a) * NCLS) * s + locbase;
        if ((s & 3) == 0) {
            const float* p  = lga + (size_t)c0 * s;
            const size_t ss = (size_t)s;
            // ---- 10 independent loads, issued back-to-back ----
            float4 v0 = *(const float4*)(p);
            float4 v1 = *(const float4*)(p + ss);
            float4 v2 = *(const float4*)(p + 2 * ss);
            float4 v3 = *(const float4*)(p + 3 * ss);
            float4 v4 = *(const float4*)(p + 4 * ss);
            float4 v5 = *(const float4*)(p + 5 * ss);
            float4 v6 = *(const float4*)(p + 6 * ss);
            float4 v7 = *(const float4*)(p + 7 * ss);
            float4 v8 = *(const float4*)(p + 8 * ss);
            float4 v9 = *(const float4*)(p + 9 * ss);
            // ---- compares in ascending class order (first-max exact) ----
            float4 m = v0;
            int mcx = c0, mcy = c0, mcz = c0, mcw = c0;
            CMP4(v1, c0 + 1); CMP4(v2, c0 + 2); CMP4(v3, c0 + 3);
            CMP4(v4, c0 + 4); CMP4(v5, c0 + 5); CMP4(v6, c0 + 6);
            CMP4(v7, c0 + 7); CMP4(v8, c0 + 8); CMP4(v9, c0 + 9);
            mj[0] = m.x; mj[1] = m.y; mj[2] = m.z; mj[3] = m.w;
            mcj[0] = mcx; mcj[1] = mcy; mcj[2] = mcz; mcj[3] = mcw;
        } else {
            for (int j = 0; j < 4; ++j) {
                const int loc = locbase + j;
                if (loc >= s) break;
                const float* l1 = lga + j;
                float mv = l1[(size_t)c0 * s];
                int mc = c0;
                for (int c = c0 + 1; c < c0 + 10; ++c) {
                    float v1s = l1[(size_t)c * s];
                    if (v1s > mv) { mv = v1s; mc = c; }
                }
                mj[j] = mv; mcj[j] = mc;
            }
        }
    }

    if (q > 0 && act) {
        smv[q - 1][t2] = make_float4(mj[0], mj[1], mj[2], mj[3]);
        smc[q - 1][t2][0] = mcj[0]; smc[q - 1][t2][1] = mcj[1];
        smc[q - 1][t2][2] = mcj[2]; smc[q - 1][t2][3] = mcj[3];
    }
    __syncthreads();

    if (q == 0 && act) {
        // merge slices in ascending class order; strict > keeps first-max
        #pragma unroll
        for (int h = 0; h < 7; ++h) {
            const float4 hv4 = smv[h][t2];
            const float* hv = (const float*)&hv4;
            #pragma unroll
            for (int j = 0; j < 4; ++j) {
                if (hv[j] > mj[j]) { mj[j] = hv[j]; mcj[j] = smc[h][t2][j]; }
            }
        }
        const size_t ob = (size_t)b * A_PAD + base + (size_t)locbase * NANCH + a;
        #pragma unroll
        for (int j = 0; j < 4; ++j) {
            const int loc = locbase + j;
            if (loc >= s) continue;
            const float mv = mj[j];
            bool pass;
            if (mv >= 0.406f)      pass = true;    // sigma >= 0.600128
            else if (mv < 0.405f)  pass = false;   // sigma <= 0.599889
            else pass = (1.0 / (1.0 + exp(-(double)mv)) >= 0.6);  // verbatim band
            unsigned kb = 0u;
            if (pass) {
                kb = __float_as_uint(mv);          // positive float -> bits order == value order
                unsigned bk = (kb - KBASE) >> KSHIFT;
                if (bk > NBUCK - 1) bk = NBUCK - 1;
                atomicAdd(&lh[bk], 1u);
            }
            const size_t o = ob + (size_t)j * NANCH;
            keys[o] = kb;
            cats[o] = (unsigned char)mcj[j];
        }
    }
    __syncthreads();

    unsigned* H = hist + (size_t)b * NBUCK;
    for (int i = tid; i < NBUCK; i += 512) {
        unsigned v = lh[i];
        if (v) atomicAdd(&H[i], v);
    }
}

// ---------------------------------------------------------------------------
// compact (select fused): (NSLC, NBATCH) x 256 = 256 blocks. Each block
// recomputes the per-batch suffix scan of hist in LDS (read-only hist ->
// identical bstar in every block; bstar = NBUCK if top bucket overflows ->
// cnt 0 -> exact fallback). Block (0,b) also writes validc[b]. Then appends
// candidates with bucket >= bstar, decoding f64 box + f32 score (verbatim).
// Selection invariant guarantees count <= MCAP. ccount pre-zeroed by memset.
// Unordered append is fine: greedy re-sorts by the combined u64 key.
// ---------------------------------------------------------------------------
__global__ __launch_bounds__(256)
void compact_kernel(const unsigned* __restrict__ keys,
                    const unsigned char* __restrict__ cats,
                    const unsigned* __restrict__ hist,
                    const float* __restrict__ rg0, const float* __restrict__ rg1,
                    const float* __restrict__ rg2, const float* __restrict__ rg3,
                    const float* __restrict__ rg4,
                    const float* __restrict__ anchors,
                    unsigned long long* __restrict__ ckey,
                    double* __restrict__ cbox,
                    float* __restrict__ cscore,
                    int* __restrict__ ccount,
                    int* __restrict__ validc)
{
    const int b = blockIdx.y;
    const int tid = threadIdx.x;

    __shared__ unsigned sa[NBUCK], sb[NBUCK];   // 32 KB
    __shared__ int bs_s;
    const unsigned* H = hist + (size_t)b * NBUCK;
    for (int i = tid; i < NBUCK; i += 256) sa[i] = H[i];
    if (tid == 0) bs_s = NBUCK;
    __syncthreads();
    unsigned* src = sa; unsigned* dst = sb;
    for (int off = 1; off < NBUCK; off <<= 1) {
        for (int i = tid; i < NBUCK; i += 256)
            dst[i] = src[i] + ((i + off < NBUCK) ? src[i + off] : 0u);
        __syncthreads();
        unsigned* t = src; src = dst; dst = t;
    }
    for (int i = tid; i < NBUCK; i += 256) {
        if (src[i] <= (unsigned)MCAP && (i == 0 || src[i - 1] > (unsigned)MCAP))
            bs_s = i;
    }
    __syncthreads();
    if (blockIdx.x == 0 && tid == 0) validc[b] = (int)src[0];
    const int bs = bs_s;

    const unsigned* K = keys + (size_t)b * A_PAD;
    const unsigned char* CT = cats + (size_t)b * A_PAD;
    const int stride = NSLC * 256;
    for (int j = blockIdx.x * 256 + tid; j < A_TOT; j += stride) {
        const unsigned k = K[j];
        if (k) {
            int bk = (int)((k - KBASE) >> KSHIFT);
            if (bk > NBUCK - 1) bk = NBUCK - 1;
            if (bk >= bs) {
                int p = atomicAdd(&ccount[b], 1);
                if (p < MCAP) {
                    unsigned pack = ((unsigned)j << 7) | (unsigned)CT[j];
                    // combined key: (mv bits desc, (j<<7|cat) asc) in one u64
                    ckey[(size_t)b * MCAP + p] =
                        ((unsigned long long)k << 24) |
                        (unsigned long long)(0xFFFFFFu - pack);
                    decode_box(b, j, rg0, rg1, rg2, rg3, rg4, anchors,
                               cbox + ((size_t)b * MCAP + p) * 4);
                    double sgd = 1.0 / (1.0 + exp(-(double)__uint_as_float(k)));
                    cscore[(size_t)b * MCAP + p] = (float)sgd;
                }
            }
        }
    }
}

// ---------------------------------------------------------------------------
// greedy: one block per batch. Bitonic sort of (combined key, slot), then the
// chunk-parallel greedy sorted scan (== reference iterative argmax+suppress
// incl. first-index tie-break) with a WAVE-PARALLEL alive-mask walk
// (pick-lowest-alive + ballot-kill == serial ascending walk), then exact
// fallback that decodes boxes on the fly. f64 IoU verbatim.
// ---------------------------------------------------------------------------
__launch_bounds__(NTH, 1)
__global__ void greedy_kernel(const unsigned* __restrict__ keys,
                              const unsigned char* __restrict__ cats,
                              const float* __restrict__ rg0, const float* __restrict__ rg1,
                              const float* __restrict__ rg2, const float* __restrict__ rg3,
                              const float* __restrict__ rg4,
                              const float* __restrict__ anchors,
                              const unsigned long long* __restrict__ ckey,
                              const double* __restrict__ cbox,
                              const float* __restrict__ cscore,
                              const int* __restrict__ ccount,
                              const int* __restrict__ validc,
                              float* __restrict__ out)
{
    const int b = blockIdx.x;
    const int tid = threadIdx.x;

    __shared__ unsigned long long skey[MCAP];   // 8 KB (reused as rvk[] in fallback)
    __shared__ unsigned sslot[MCAP];            // 4 KB (reused as ri[] in fallback)
    __shared__ alignas(16) char ubuf[20480];
    __shared__ int acc_s;

    const int cnt_raw = ccount[b];
    const int cnt = cnt_raw < MCAP ? cnt_raw : MCAP;
    const int valid = validc[b];

    for (int i = tid; i < MCAP; i += NTH) {
        if (i < cnt) {
            skey[i] = ckey[(size_t)b * MCAP + i];
            sslot[i] = (unsigned)i;
        } else {
            skey[i] = 0ull;
            sslot[i] = 0xFFFFFFFFu;
        }
    }
    __syncthreads();

    // ---- bitonic sort (combined key desc) ------------------------------
    for (int k = 2; k <= MCAP; k <<= 1) {
        for (int j2 = k >> 1; j2 > 0; j2 >>= 1) {
            for (int i = tid; i < MCAP; i += NTH) {
                int ixj = i ^ j2;
                if (ixj > i) {
                    unsigned long long ka = skey[i], kb2 = skey[ixj];
                    unsigned pa = sslot[i], pb = sslot[ixj];
                    bool before = (ka > kb2) || (ka == kb2 && pa < pb);
                    bool dir = ((i & k) == 0);
                    if (before != dir) {
                        skey[i] = kb2; skey[ixj] = ka;
                        sslot[i] = pb; sslot[ixj] = pa;
                    }
                }
            }
            __syncthreads();
        }
    }

    // ---- LDS layout for accepted/out/chunk -----------------------------
    double* aX1 = (double*)ubuf;                           // 200*8*5 = 8000
    double* aY1 = aX1 + NOUT;
    double* aX2 = aY1 + NOUT;
    double* aY2 = aX2 + NOUT;
    double* aAR = aY2 + NOUT;
    int*   aCT  = (int*)(ubuf + 8000);                     // 800
    float* obuf = (float*)(ubuf + 8800);                   // 4800
    double* cSX1 = (double*)(ubuf + 13600);                // 64*8 each
    double* cSY1 = (double*)(ubuf + 14112);
    double* cSX2 = (double*)(ubuf + 14624);
    double* cSY2 = (double*)(ubuf + 15136);
    double* cAR2 = (double*)(ubuf + 15648);
    double (*cUB)[4] = (double(*)[4])(ubuf + 16160);       // 64*32 = 2048
    int* cCat = (int*)(ubuf + 18208);                      // 256
    unsigned long long* cMask = (unsigned long long*)(ubuf + 18464);  // 512
    int* cSup = (int*)(ubuf + 18976);                      // 256
    float* cSc = (float*)(ubuf + 19232);                   // 256

    for (int i = tid; i < NOUT * 6; i += NTH)
        obuf[i] = ((i % 6) == 5) ? -1.0f : 0.0f;
    __syncthreads();

    // ---- chunk-parallel greedy sorted scan -----------------------------
    int acc = 0;
    for (int c0 = 0; c0 < cnt && acc < NOUT; c0 += CHUNK) {
        const int n = (cnt - c0) < CHUNK ? (cnt - c0) : CHUNK;

        if (tid < n) {
            unsigned long long ke = skey[c0 + tid];
            unsigned pack = 0xFFFFFFu - (unsigned)(ke & 0xFFFFFFull);
            int cat = (int)(pack & 127u);
            int sl = (int)sslot[c0 + tid];
            const double* bb = cbox + ((size_t)b * MCAP + sl) * 4;
            double b0 = bb[0], b1 = bb[1], b2 = bb[2], b3 = bb[3];
            cUB[tid][0] = b0; cUB[tid][1] = b1; cUB[tid][2] = b2; cUB[tid][3] = b3;
            double shift = (double)cat * 1280.0;
            double x1 = b0 + shift, y1 = b1 + shift;
            double x2 = b2 + shift, y2 = b3 + shift;
            cSX1[tid] = x1; cSY1[tid] = y1; cSX2[tid] = x2; cSY2[tid] = y2;
            cAR2[tid] = (x2 - x1) * (y2 - y1);
            cCat[tid] = cat;
            cSc[tid] = cscore[(size_t)b * MCAP + sl];
            cMask[tid] = 0ull;
            cSup[tid] = 0;
        }
        __syncthreads();

        // (a) candidates vs accepted list: 16 threads per candidate
        {
            const int i = tid >> 4;
            if (i < n) {
                const int cat = cCat[i];
                const double x1 = cSX1[i], y1 = cSY1[i];
                const double x2 = cSX2[i], y2 = cSY2[i];
                const double areaj = cAR2[i];
                bool f = false;
                for (int r = (tid & 15); r < acc; r += 16) {
                    int cd = aCT[r] - cat; if (cd < 0) cd = -cd;
                    if (cd <= 4) {
                        double ix1 = aX1[r] > x1 ? aX1[r] : x1;
                        double iy1 = aY1[r] > y1 ? aY1[r] : y1;
                        double ix2 = aX2[r] < x2 ? aX2[r] : x2;
                        double iy2 = aY2[r] < y2 ? aY2[r] : y2;
                        double iw = ix2 - ix1; if (iw < 0.0) iw = 0.0;
                        double ih = iy2 - iy1; if (ih < 0.0) ih = 0.0;
                        double inter = iw * ih;
                        double iou = inter / (aAR[r] + areaj - inter + 1e-9);
                        if (iou > 0.5) f = true;
                    }
                }
                if (f) cSup[i] = 1;
            }
        }

        // (b) intra-chunk 64x64 suppression mask (j < i; j as would-be pick)
        for (int p = tid; p < (n << 6); p += NTH) {
            const int i = p >> 6, j = p & 63;
            if (j < i && j < n) {
                int cd = cCat[j] - cCat[i]; if (cd < 0) cd = -cd;
                if (cd <= 4) {
                    double x1 = cSX1[i], y1 = cSY1[i];
                    double x2 = cSX2[i], y2 = cSY2[i];
                    double ix1 = cSX1[j] > x1 ? cSX1[j] : x1;
                    double iy1 = cSY1[j] > y1 ? cSY1[j] : y1;
                    double ix2 = cSX2[j] < x2 ? cSX2[j] : x2;
                    double iy2 = cSY2[j] < y2 ? cSY2[j] : y2;
                    double iw = ix2 - ix1; if (iw < 0.0) iw = 0.0;
                    double ih = iy2 - iy1; if (ih < 0.0) ih = 0.0;
                    double inter = iw * ih;
                    double iou = inter / (cAR2[j] + cAR2[i] - inter + 1e-9);
                    if (iou > 0.5)
                        atomicOr(&cMask[i], 1ull << j);
                }
            }
        }
        __syncthreads();

        // (c) wave-parallel alive-mask walk (first wave only).
        // pick-lowest-alive + ballot-kill == the serial ascending walk:
        // victims are removed before ever being considered, picks ascend.
        if (tid < 64) {
            const int lane = tid;
            unsigned long long m = 0ull;
            int supv = 1;
            if (lane < n) { m = cMask[lane]; supv = cSup[lane]; }
            unsigned long long alive = __ballot(lane < n && !supv);
            unsigned long long am = 0ull;
            int a2 = acc;
            while (alive && a2 < NOUT) {
                int i = (int)__ffsll((unsigned long long)alive) - 1;
                am |= 1ull << i;
                ++a2;
                unsigned long long kill = __ballot((m >> i) & 1ull);
                alive &= ~(kill | (1ull << i));
            }
            // parallel append of accepted candidates (order preserved by pos)
            if (am & (1ull << lane)) {
                int pos = acc + (int)__popcll(am & ((1ull << lane) - 1ull));
                aX1[pos] = cSX1[lane]; aY1[pos] = cSY1[lane];
                aX2[pos] = cSX2[lane]; aY2[pos] = cSY2[lane];
                aAR[pos] = cAR2[lane]; aCT[pos] = cCat[lane];
                float* o = obuf + pos * 6;
                o[0] = (float)cUB[lane][0]; o[1] = (float)cUB[lane][1];
                o[2] = (float)cUB[lane][2]; o[3] = (float)cUB[lane][3];
                o[4] = cSc[lane];
                o[5] = (float)cCat[lane];
            }
            if (lane == 0) acc_s = acc + (int)__popcll(am);
        }
        __syncthreads();
        acc = acc_s;
    }

    // ---- exact fallback (pathological only) ----------------------------
    if (acc < NOUT && cnt < valid) {
        unsigned* rvk = (unsigned*)skey;
        int*      ri  = (int*)sslot;
        const unsigned* K = keys + (size_t)b * A_PAD;
        const unsigned char* CT = cats + (size_t)b * A_PAD;
        while (acc < NOUT) {
            unsigned best = 0u;
            int bi = 0x7fffffff;
            for (int j = tid; j < A_TOT; j += NTH) {
                const unsigned k = K[j];
                if (k) {
                    int cat = (int)CT[j];
                    double bb[4];
                    decode_box(b, j, rg0, rg1, rg2, rg3, rg4, anchors, bb);
                    double shift = (double)cat * 1280.0;
                    double x1 = bb[0] + shift, y1 = bb[1] + shift;
                    double x2 = bb[2] + shift, y2 = bb[3] + shift;
                    double areaj = (x2 - x1) * (y2 - y1);
                    bool dead = false;
                    for (int r = 0; r < acc && !dead; ++r) {
                        int cd = aCT[r] - cat; if (cd < 0) cd = -cd;
                        if (cd <= 4) {
                            double ix1 = aX1[r] > x1 ? aX1[r] : x1;
                            double iy1 = aY1[r] > y1 ? aY1[r] : y1;
                            double ix2 = aX2[r] < x2 ? aX2[r] : x2;
                            double iy2 = aY2[r] < y2 ? aY2[r] : y2;
                            double iw = ix2 - ix1; if (iw < 0.0) iw = 0.0;
                            double ih = iy2 - iy1; if (ih < 0.0) ih = 0.0;
                            double inter = iw * ih;
                            double iou = inter / (aAR[r] + areaj - inter + 1e-9);
                            if (iou > 0.5) dead = true;
                        }
                    }
                    if (!dead && k > best) { best = k; bi = j; }  // j ascending: ties keep first index
                }
            }
            rvk[tid] = best; ri[tid] = bi;
            __syncthreads();
            for (int off = NTH / 2; off > 0; off >>= 1) {
                if (tid < off) {
                    if (rvk[tid + off] > rvk[tid] ||
                        (rvk[tid + off] == rvk[tid] && ri[tid + off] < ri[tid])) {
                        rvk[tid] = rvk[tid + off]; ri[tid] = ri[tid + off];
                    }
                }
                __syncthreads();
            }
            if (rvk[0] == 0u) break;
            if (tid == 0) {
                int j = ri[0];
                int cat = (int)CT[j];
                double bb[4];
                decode_box(b, j, rg0, rg1, rg2, rg3, rg4, anchors, bb);
                double shift = (double)cat * 1280.0;
                double x1 = bb[0] + shift, y1 = bb[1] + shift;
                double x2 = bb[2] + shift, y2 = bb[3] + shift;
                aX1[acc] = x1; aY1[acc] = y1; aX2[acc] = x2; aY2[acc] = y2;
                aAR[acc] = (x2 - x1) * (y2 - y1); aCT[acc] = cat;
                float* o = obuf + acc * 6;
                o[0] = (float)bb[0]; o[1] = (float)bb[1];
                o[2] = (float)bb[2]; o[3] = (float)bb[3];
                o[4] = (float)(1.0 / (1.0 + exp(-(double)__uint_as_float(rvk[0]))));
                o[5] = (float)cat;
                acc_s = acc + 1;
            }
            __syncthreads();
            acc = acc_s;
        }
    }
    __syncthreads();

    // ---- write output ---------------------------------------------------
    float* O = out + (size_t)b * NOUT * 6;
    for (int i = tid; i < NOUT * 6; i += NTH) O[i] = obuf[i];
}

extern "C" void kernel_launch(void* const* d_in, const int* in_sizes, int n_in,
                              void* d_out, int out_size, void* d_ws, size_t ws_size,
                              hipStream_t stream)
{
    // input dict order is interleaved: logits_i, regress_i pairs, anchors last
    const float* lg0 = (const float*)d_in[0];
    const float* rg0 = (const float*)d_in[1];
    const float* lg1 = (const float*)d_in[2];
    const float* rg1 = (const float*)d_in[3];
    const float* lg2 = (const float*)d_in[4];
    const float* rg2 = (const float*)d_in[5];
    const float* lg3 = (const float*)d_in[6];
    const float* rg3 = (const float*)d_in[7];
    const float* lg4 = (const float*)d_in[8];
    const float* rg4 = (const float*)d_in[9];
    const float* anchors = (const float*)d_in[10];

    char* ws = (char*)d_ws;
    unsigned*      keys   = (unsigned*)ws;                         // 8*A_PAD*4 = 2,455,296
    unsigned char* cats   = (unsigned char*)(ws + 2455296);        // 8*A_PAD   =   613,824
    unsigned*      hist   = (unsigned*)(ws + 3069184);             // 8*4096*4  =   131,072
    int*           ccount = (int*)(ws + 3200256);                  // 32 (contiguous after hist for one memset)
    int*           validc = (int*)(ws + 3200320);                  // 32
    unsigned long long* ckey = (unsigned long long*)(ws + 3200384);// 8*1024*8  =    65,536
    double*        cbox   = (double*)(ws + 3265920);               // 8*1024*32 =   262,144
    float*         cscore = (float*)(ws + 3528064);                // 8*1024*4  =    32,768

    hipMemsetAsync(hist, 0, 131072 + 32, stream);

    prep_kernel<<<dim3(NCHUNKS, NANCH, NBATCH), 512, 0, stream>>>(
        lg0, lg1, lg2, lg3, lg4, keys, cats, hist);

    compact_kernel<<<dim3(NSLC, NBATCH), 256, 0, stream>>>(
        keys, cats, hist, rg0, rg1, rg2, rg3, rg4, anchors,
        ckey, cbox, cscore, ccount, validc);

    greedy_kernel<<<NBATCH, NTH, 0, stream>>>(
        keys, cats, rg0, rg1, rg2, rg3, rg4, anchors,
        ckey, cbox, cscore, ccount, validc, (float*)d_out);
}

// Round 8
// 393.382 us; speedup vs baseline: 1.0356x; 1.0356x over previous
//
#include <hip/hip_runtime.h>
#include <cmath>

#define A_TOT 76725
#define A_PAD 76728   // multiple of 4
#define NBATCH 8
#define NCLS 80
#define NANCH 9
#define NOUT 200

#define MCAP 1024     // compacted-candidate capacity (power of two, bitonic)
#define NTH 1024
#define NBUCK 4096
#define CHUNK 64
#define NSLC 32       // parallel slices per batch for compact
#define KBASE 0x3EC00000u   // f32 bits of 0.375 — below any passing key (>=~0.40547)
#define KSHIFT 16
#define NCHUNKS 36    // 25 (lvl0) + 7 (lvl1) + 2 (lvl2) + 1 (lvl3) + 1 (lvl4)

// ---------------------------------------------------------------------------
// f64 box decode, identical expressions to the verified rounds (absmax 0.0)
// — do not reorder these ops. Used by compact (hot, <=1024/batch) and by the
// greedy fallback (pathological only).
// ---------------------------------------------------------------------------
__device__ __forceinline__ void decode_box(int b, int j,
                                           const float* __restrict__ rg0,
                                           const float* __restrict__ rg1,
                                           const float* __restrict__ rg2,
                                           const float* __restrict__ rg3,
                                           const float* __restrict__ rg4,
                                           const float* __restrict__ anchors,
                                           double* __restrict__ o4)
{
    int s, base;
    const float* rg;
    if (j >= 76500)      { s = 25;   base = 76500; rg = rg4; }
    else if (j >= 75600) { s = 100;  base = 75600; rg = rg3; }
    else if (j >= 72000) { s = 400;  base = 72000; rg = rg2; }
    else if (j >= 57600) { s = 1600; base = 57600; rg = rg1; }
    else                 { s = 6400; base = 0;     rg = rg0; }
    const int rem = j - base;
    const int loc = rem / 9;
    const int aa  = rem - loc * 9;
    const size_t ro = ((size_t)(b * NANCH + aa) * 4) * s + loc;
    const float f0 = rg[ro];
    const float f1 = rg[ro + (size_t)s];
    const float f2 = rg[ro + 2 * (size_t)s];
    const float f3 = rg[ro + 3 * (size_t)s];

    double d0 = (double)f0, d1 = (double)f1, d2 = (double)f2, d3 = (double)f3;
    const float4 av = *(const float4*)(anchors + (size_t)j * 4);
    double ax1 = (double)av.x, ay1 = (double)av.y;
    double ax2 = (double)av.z, ay2 = (double)av.w;
    double aw = ax2 - ax1, ah = ay2 - ay1;
    double acx = ax1 + 0.5 * aw, acy = ay1 + 0.5 * ah;
    double cx = acx + d0 * aw, cy = acy + d1 * ah;
    double w = aw * exp(d2), h = ah * exp(d3);
    o4[0] = cx - 0.5 * w;
    o4[1] = cy - 0.5 * h;
    o4[2] = cx + 0.5 * w;
    o4[3] = cy + 0.5 * h;
}

// ---------------------------------------------------------------------------
// prep: BYTE-IDENTICAL to round 7 (launch_bounds(512,4) + named v0..v9
// register-batched loads). grid (36 chunks-of-256-locations, 9 anchors,
// 8 batch) x 512 threads. Class dim split across EIGHT 64-thread slices
// (10 classes each), merged via LDS in ascending slice order with strict->
// (first-max-index preserved). Emits key = f32 logit bits (0 if below
// threshold) + cat, fuses the per-batch bucket histogram via LDS atomics.
// Threshold: exact band filter; only mv in (0.405,0.406) evaluates the
// verbatim f64 predicate. f32-bit ordering == f64 sigmoid ordering.
// ---------------------------------------------------------------------------
#define CMP4(vv, cc)                                            \
    do {                                                        \
        if ((vv).x > m.x) { m.x = (vv).x; mcx = (cc); }         \
        if ((vv).y > m.y) { m.y = (vv).y; mcy = (cc); }         \
        if ((vv).z > m.z) { m.z = (vv).z; mcz = (cc); }         \
        if ((vv).w > m.w) { m.w = (vv).w; mcw = (cc); }         \
    } while (0)

__global__ __launch_bounds__(512, 4)
void prep_kernel(const float* __restrict__ lg0, const float* __restrict__ lg1,
                 const float* __restrict__ lg2, const float* __restrict__ lg3,
                 const float* __restrict__ lg4,
                 unsigned* __restrict__ keys,
                 unsigned char* __restrict__ cats,
                 unsigned* __restrict__ hist)
{
    const int cx = blockIdx.x;
    const int a  = blockIdx.y;
    const int b  = blockIdx.z;
    int lvl, local;
    if (cx < 25)      { lvl = 0; local = cx; }
    else if (cx < 32) { lvl = 1; local = cx - 25; }
    else if (cx < 34) { lvl = 2; local = cx - 32; }
    else if (cx < 35) { lvl = 3; local = 0; }
    else              { lvl = 4; local = 0; }

    const int   sarr[5] = {6400, 1600, 400, 100, 25};
    const int   barr[5] = {0, 57600, 72000, 75600, 76500};
    const float* lgs[5] = {lg0, lg1, lg2, lg3, lg4};
    const int s = sarr[lvl], base = barr[lvl];
    const float* lg = lgs[lvl];

    __shared__ unsigned lh[NBUCK];       // 16 KB
    __shared__ float4   smv[7][64];      // 7 KB
    __shared__ int      smc[7][64][4];   // 7 KB

    const int tid = threadIdx.x;
    for (int i = tid; i < NBUCK; i += 512) lh[i] = 0u;

    const int t2 = tid & 63;            // 64 location-groups x 4 locs = 256 locs
    const int q  = tid >> 6;            // class slice 0..7 (10 classes each)
    const int c0 = q * 10;
    const int locbase = local * 256 + t2 * 4;
    const bool act = locbase < s;

    float mj[4]  = {-1e30f, -1e30f, -1e30f, -1e30f};
    int   mcj[4] = {0, 0, 0, 0};

    if (act) {
        const float* lga = lg + ((size_t)(b * NANCH + a) * NCLS) * s + locbase;
        if ((s & 3) == 0) {
            const float* p  = lga + (size_t)c0 * s;
            const size_t ss = (size_t)s;
            // ---- 10 independent loads, issued back-to-back ----
            float4 v0 = *(const float4*)(p);
            float4 v1 = *(const float4*)(p + ss);
            float4 v2 = *(const float4*)(p + 2 * ss);
            float4 v3 = *(const float4*)(p + 3 * ss);
            float4 v4 = *(const float4*)(p + 4 * ss);
            float4 v5 = *(const float4*)(p + 5 * ss);
            float4 v6 = *(const float4*)(p + 6 * ss);
            float4 v7 = *(const float4*)(p + 7 * ss);
            float4 v8 = *(const float4*)(p + 8 * ss);
            float4 v9 = *(const float4*)(p + 9 * ss);
            // ---- compares in ascending class order (first-max exact) ----
            float4 m = v0;
            int mcx = c0, mcy = c0, mcz = c0, mcw = c0;
            CMP4(v1, c0 + 1); CMP4(v2, c0 + 2); CMP4(v3, c0 + 3);
            CMP4(v4, c0 + 4); CMP4(v5, c0 + 5); CMP4(v6, c0 + 6);
            CMP4(v7, c0 + 7); CMP4(v8, c0 + 8); CMP4(v9, c0 + 9);
            mj[0] = m.x; mj[1] = m.y; mj[2] = m.z; mj[3] = m.w;
            mcj[0] = mcx; mcj[1] = mcy; mcj[2] = mcz; mcj[3] = mcw;
        } else {
            for (int j = 0; j < 4; ++j) {
                const int loc = locbase + j;
                if (loc >= s) break;
                const float* l1 = lga + j;
                float mv = l1[(size_t)c0 * s];
                int mc = c0;
                for (int c = c0 + 1; c < c0 + 10; ++c) {
                    float v1s = l1[(size_t)c * s];
                    if (v1s > mv) { mv = v1s; mc = c; }
                }
                mj[j] = mv; mcj[j] = mc;
            }
        }
    }

    if (q > 0 && act) {
        smv[q - 1][t2] = make_float4(mj[0], mj[1], mj[2], mj[3]);
        smc[q - 1][t2][0] = mcj[0]; smc[q - 1][t2][1] = mcj[1];
        smc[q - 1][t2][2] = mcj[2]; smc[q - 1][t2][3] = mcj[3];
    }
    __syncthreads();

    if (q == 0 && act) {
        // merge slices in ascending class order; strict > keeps first-max
        #pragma unroll
        for (int h = 0; h < 7; ++h) {
            const float4 hv4 = smv[h][t2];
            const float* hv = (const float*)&hv4;
            #pragma unroll
            for (int j = 0; j < 4; ++j) {
                if (hv[j] > mj[j]) { mj[j] = hv[j]; mcj[j] = smc[h][t2][j]; }
            }
        }
        const size_t ob = (size_t)b * A_PAD + base + (size_t)locbase * NANCH + a;
        #pragma unroll
        for (int j = 0; j < 4; ++j) {
            const int loc = locbase + j;
            if (loc >= s) continue;
            const float mv = mj[j];
            bool pass;
            if (mv >= 0.406f)      pass = true;    // sigma >= 0.600128
            else if (mv < 0.405f)  pass = false;   // sigma <= 0.599889
            else pass = (1.0 / (1.0 + exp(-(double)mv)) >= 0.6);  // verbatim band
            unsigned kb = 0u;
            if (pass) {
                kb = __float_as_uint(mv);          // positive float -> bits order == value order
                unsigned bk = (kb - KBASE) >> KSHIFT;
                if (bk > NBUCK - 1) bk = NBUCK - 1;
                atomicAdd(&lh[bk], 1u);
            }
            const size_t o = ob + (size_t)j * NANCH;
            keys[o] = kb;
            cats[o] = (unsigned char)mcj[j];
        }
    }
    __syncthreads();

    unsigned* H = hist + (size_t)b * NBUCK;
    for (int i = tid; i < NBUCK; i += 512) {
        unsigned v = lh[i];
        if (v) atomicAdd(&H[i], v);
    }
}

// ---------------------------------------------------------------------------
// select: per-batch suffix scan of hist -> threshold bucket bstar such that
// suffix count <= MCAP (bstar = NBUCK if even the top bucket overflows ->
// cnt 0 -> exact fallback path). 8 blocks x 1024 threads, scan runs ONCE
// per batch (the R7 fusion ran it 32x at 256 threads — 87 us regression).
// ---------------------------------------------------------------------------
__global__ __launch_bounds__(NTH)
void select_kernel(const unsigned* __restrict__ hist,
                   int* __restrict__ bstar,
                   int* __restrict__ validc)
{
    const int b = blockIdx.x;
    const int tid = threadIdx.x;
    __shared__ unsigned sa[NBUCK], sb[NBUCK];
    __shared__ int bs_s;
    const unsigned* H = hist + (size_t)b * NBUCK;
    for (int i = tid; i < NBUCK; i += NTH) sa[i] = H[i];
    if (tid == 0) bs_s = NBUCK;
    __syncthreads();
    unsigned* src = sa; unsigned* dst = sb;
    for (int off = 1; off < NBUCK; off <<= 1) {
        for (int i = tid; i < NBUCK; i += NTH)
            dst[i] = src[i] + ((i + off < NBUCK) ? src[i + off] : 0u);
        __syncthreads();
        unsigned* t = src; src = dst; dst = t;
    }
    for (int i = tid; i < NBUCK; i += NTH) {
        if (src[i] <= (unsigned)MCAP && (i == 0 || src[i - 1] > (unsigned)MCAP))
            bs_s = i;
    }
    __syncthreads();
    if (tid == 0) { bstar[b] = bs_s; validc[b] = (int)src[0]; }
}

// ---------------------------------------------------------------------------
// compact: (NSLC, NBATCH) x 256 = 256 blocks, zero LDS (the R2-R6 proven
// shape). Append candidates with bucket >= bstar, decoding f64 box + f32
// score (verbatim expressions). Selection invariant guarantees count <=
// MCAP. ccount pre-zeroed by memset. Unordered append is fine: greedy
// re-sorts by the combined (key desc, (j<<7|cat) asc) u64.
// ---------------------------------------------------------------------------
__global__ __launch_bounds__(256)
void compact_kernel(const unsigned* __restrict__ keys,
                    const unsigned char* __restrict__ cats,
                    const int* __restrict__ bstar,
                    const float* __restrict__ rg0, const float* __restrict__ rg1,
                    const float* __restrict__ rg2, const float* __restrict__ rg3,
                    const float* __restrict__ rg4,
                    const float* __restrict__ anchors,
                    unsigned long long* __restrict__ ckey,
                    double* __restrict__ cbox,
                    float* __restrict__ cscore,
                    int* __restrict__ ccount)
{
    const int b = blockIdx.y;
    const int tid = threadIdx.x;
    const unsigned* K = keys + (size_t)b * A_PAD;
    const unsigned char* CT = cats + (size_t)b * A_PAD;
    const int bs = bstar[b];
    const int stride = NSLC * 256;
    for (int j = blockIdx.x * 256 + tid; j < A_TOT; j += stride) {
        const unsigned k = K[j];
        if (k) {
            int bk = (int)((k - KBASE) >> KSHIFT);
            if (bk > NBUCK - 1) bk = NBUCK - 1;
            if (bk >= bs) {
                int p = atomicAdd(&ccount[b], 1);
                if (p < MCAP) {
                    unsigned pack = ((unsigned)j << 7) | (unsigned)CT[j];
                    // combined key: (mv bits desc, (j<<7|cat) asc) in one u64
                    ckey[(size_t)b * MCAP + p] =
                        ((unsigned long long)k << 24) |
                        (unsigned long long)(0xFFFFFFu - pack);
                    decode_box(b, j, rg0, rg1, rg2, rg3, rg4, anchors,
                               cbox + ((size_t)b * MCAP + p) * 4);
                    double sgd = 1.0 / (1.0 + exp(-(double)__uint_as_float(k)));
                    cscore[(size_t)b * MCAP + p] = (float)sgd;
                }
            }
        }
    }
}

// ---------------------------------------------------------------------------
// greedy: one block per batch. Bitonic sort of (combined key, slot), then the
// chunk-parallel greedy sorted scan (== reference iterative argmax+suppress
// incl. first-index tie-break) with a WAVE-PARALLEL alive-mask walk
// (pick-lowest-alive + ballot-kill == serial ascending walk), then exact
// fallback that decodes boxes on the fly. f64 IoU verbatim.
// ---------------------------------------------------------------------------
__launch_bounds__(NTH, 1)
__global__ void greedy_kernel(const unsigned* __restrict__ keys,
                              const unsigned char* __restrict__ cats,
                              const float* __restrict__ rg0, const float* __restrict__ rg1,
                              const float* __restrict__ rg2, const float* __restrict__ rg3,
                              const float* __restrict__ rg4,
                              const float* __restrict__ anchors,
                              const unsigned long long* __restrict__ ckey,
                              const double* __restrict__ cbox,
                              const float* __restrict__ cscore,
                              const int* __restrict__ ccount,
                              const int* __restrict__ validc,
                              float* __restrict__ out)
{
    const int b = blockIdx.x;
    const int tid = threadIdx.x;

    __shared__ unsigned long long skey[MCAP];   // 8 KB (reused as rvk[] in fallback)
    __shared__ unsigned sslot[MCAP];            // 4 KB (reused as ri[] in fallback)
    __shared__ alignas(16) char ubuf[20480];
    __shared__ int acc_s;

    const int cnt_raw = ccount[b];
    const int cnt = cnt_raw < MCAP ? cnt_raw : MCAP;
    const int valid = validc[b];

    for (int i = tid; i < MCAP; i += NTH) {
        if (i < cnt) {
            skey[i] = ckey[(size_t)b * MCAP + i];
            sslot[i] = (unsigned)i;
        } else {
            skey[i] = 0ull;
            sslot[i] = 0xFFFFFFFFu;
        }
    }
    __syncthreads();

    // ---- bitonic sort (combined key desc) ------------------------------
    for (int k = 2; k <= MCAP; k <<= 1) {
        for (int j2 = k >> 1; j2 > 0; j2 >>= 1) {
            for (int i = tid; i < MCAP; i += NTH) {
                int ixj = i ^ j2;
                if (ixj > i) {
                    unsigned long long ka = skey[i], kb2 = skey[ixj];
                    unsigned pa = sslot[i], pb = sslot[ixj];
                    bool before = (ka > kb2) || (ka == kb2 && pa < pb);
                    bool dir = ((i & k) == 0);
                    if (before != dir) {
                        skey[i] = kb2; skey[ixj] = ka;
                        sslot[i] = pb; sslot[ixj] = pa;
                    }
                }
            }
            __syncthreads();
        }
    }

    // ---- LDS layout for accepted/out/chunk -----------------------------
    double* aX1 = (double*)ubuf;                           // 200*8*5 = 8000
    double* aY1 = aX1 + NOUT;
    double* aX2 = aY1 + NOUT;
    double* aY2 = aX2 + NOUT;
    double* aAR = aY2 + NOUT;
    int*   aCT  = (int*)(ubuf + 8000);                     // 800
    float* obuf = (float*)(ubuf + 8800);                   // 4800
    double* cSX1 = (double*)(ubuf + 13600);                // 64*8 each
    double* cSY1 = (double*)(ubuf + 14112);
    double* cSX2 = (double*)(ubuf + 14624);
    double* cSY2 = (double*)(ubuf + 15136);
    double* cAR2 = (double*)(ubuf + 15648);
    double (*cUB)[4] = (double(*)[4])(ubuf + 16160);       // 64*32 = 2048
    int* cCat = (int*)(ubuf + 18208);                      // 256
    unsigned long long* cMask = (unsigned long long*)(ubuf + 18464);  // 512
    int* cSup = (int*)(ubuf + 18976);                      // 256
    float* cSc = (float*)(ubuf + 19232);                   // 256

    for (int i = tid; i < NOUT * 6; i += NTH)
        obuf[i] = ((i % 6) == 5) ? -1.0f : 0.0f;
    __syncthreads();

    // ---- chunk-parallel greedy sorted scan -----------------------------
    int acc = 0;
    for (int c0 = 0; c0 < cnt && acc < NOUT; c0 += CHUNK) {
        const int n = (cnt - c0) < CHUNK ? (cnt - c0) : CHUNK;

        if (tid < n) {
            unsigned long long ke = skey[c0 + tid];
            unsigned pack = 0xFFFFFFu - (unsigned)(ke & 0xFFFFFFull);
            int cat = (int)(pack & 127u);
            int sl = (int)sslot[c0 + tid];
            const double* bb = cbox + ((size_t)b * MCAP + sl) * 4;
            double b0 = bb[0], b1 = bb[1], b2 = bb[2], b3 = bb[3];
            cUB[tid][0] = b0; cUB[tid][1] = b1; cUB[tid][2] = b2; cUB[tid][3] = b3;
            double shift = (double)cat * 1280.0;
            double x1 = b0 + shift, y1 = b1 + shift;
            double x2 = b2 + shift, y2 = b3 + shift;
            cSX1[tid] = x1; cSY1[tid] = y1; cSX2[tid] = x2; cSY2[tid] = y2;
            cAR2[tid] = (x2 - x1) * (y2 - y1);
            cCat[tid] = cat;
            cSc[tid] = cscore[(size_t)b * MCAP + sl];
            cMask[tid] = 0ull;
            cSup[tid] = 0;
        }
        __syncthreads();

        // (a) candidates vs accepted list: 16 threads per candidate
        {
            const int i = tid >> 4;
            if (i < n) {
                const int cat = cCat[i];
                const double x1 = cSX1[i], y1 = cSY1[i];
                const double x2 = cSX2[i], y2 = cSY2[i];
                const double areaj = cAR2[i];
                bool f = false;
                for (int r = (tid & 15); r < acc; r += 16) {
                    int cd = aCT[r] - cat; if (cd < 0) cd = -cd;
                    if (cd <= 4) {
                        double ix1 = aX1[r] > x1 ? aX1[r] : x1;
                        double iy1 = aY1[r] > y1 ? aY1[r] : y1;
                        double ix2 = aX2[r] < x2 ? aX2[r] : x2;
                        double iy2 = aY2[r] < y2 ? aY2[r] : y2;
                        double iw = ix2 - ix1; if (iw < 0.0) iw = 0.0;
                        double ih = iy2 - iy1; if (ih < 0.0) ih = 0.0;
                        double inter = iw * ih;
                        double iou = inter / (aAR[r] + areaj - inter + 1e-9);
                        if (iou > 0.5) f = true;
                    }
                }
                if (f) cSup[i] = 1;
            }
        }

        // (b) intra-chunk 64x64 suppression mask (j < i; j as would-be pick)
        for (int p = tid; p < (n << 6); p += NTH) {
            const int i = p >> 6, j = p & 63;
            if (j < i && j < n) {
                int cd = cCat[j] - cCat[i]; if (cd < 0) cd = -cd;
                if (cd <= 4) {
                    double x1 = cSX1[i], y1 = cSY1[i];
                    double x2 = cSX2[i], y2 = cSY2[i];
                    double ix1 = cSX1[j] > x1 ? cSX1[j] : x1;
                    double iy1 = cSY1[j] > y1 ? cSY1[j] : y1;
                    double ix2 = cSX2[j] < x2 ? cSX2[j] : x2;
                    double iy2 = cSY2[j] < y2 ? cSY2[j] : y2;
                    double iw = ix2 - ix1; if (iw < 0.0) iw = 0.0;
                    double ih = iy2 - iy1; if (ih < 0.0) ih = 0.0;
                    double inter = iw * ih;
                    double iou = inter / (cAR2[j] + cAR2[i] - inter + 1e-9);
                    if (iou > 0.5)
                        atomicOr(&cMask[i], 1ull << j);
                }
            }
        }
        __syncthreads();

        // (c) wave-parallel alive-mask walk (first wave only).
        // pick-lowest-alive + ballot-kill == the serial ascending walk:
        // victims are removed before ever being considered, picks ascend.
        if (tid < 64) {
            const int lane = tid;
            unsigned long long m = 0ull;
            int supv = 1;
            if (lane < n) { m = cMask[lane]; supv = cSup[lane]; }
            unsigned long long alive = __ballot(lane < n && !supv);
            unsigned long long am = 0ull;
            int a2 = acc;
            while (alive && a2 < NOUT) {
                int i = (int)__ffsll((unsigned long long)alive) - 1;
                am |= 1ull << i;
                ++a2;
                unsigned long long kill = __ballot((m >> i) & 1ull);
                alive &= ~(kill | (1ull << i));
            }
            // parallel append of accepted candidates (order preserved by pos)
            if (am & (1ull << lane)) {
                int pos = acc + (int)__popcll(am & ((1ull << lane) - 1ull));
                aX1[pos] = cSX1[lane]; aY1[pos] = cSY1[lane];
                aX2[pos] = cSX2[lane]; aY2[pos] = cSY2[lane];
                aAR[pos] = cAR2[lane]; aCT[pos] = cCat[lane];
                float* o = obuf + pos * 6;
                o[0] = (float)cUB[lane][0]; o[1] = (float)cUB[lane][1];
                o[2] = (float)cUB[lane][2]; o[3] = (float)cUB[lane][3];
                o[4] = cSc[lane];
                o[5] = (float)cCat[lane];
            }
            if (lane == 0) acc_s = acc + (int)__popcll(am);
        }
        __syncthreads();
        acc = acc_s;
    }

    // ---- exact fallback (pathological only) ----------------------------
    if (acc < NOUT && cnt < valid) {
        unsigned* rvk = (unsigned*)skey;
        int*      ri  = (int*)sslot;
        const unsigned* K = keys + (size_t)b * A_PAD;
        const unsigned char* CT = cats + (size_t)b * A_PAD;
        while (acc < NOUT) {
            unsigned best = 0u;
            int bi = 0x7fffffff;
            for (int j = tid; j < A_TOT; j += NTH) {
                const unsigned k = K[j];
                if (k) {
                    int cat = (int)CT[j];
                    double bb[4];
                    decode_box(b, j, rg0, rg1, rg2, rg3, rg4, anchors, bb);
                    double shift = (double)cat * 1280.0;
                    double x1 = bb[0] + shift, y1 = bb[1] + shift;
                    double x2 = bb[2] + shift, y2 = bb[3] + shift;
                    double areaj = (x2 - x1) * (y2 - y1);
                    bool dead = false;
                    for (int r = 0; r < acc && !dead; ++r) {
                        int cd = aCT[r] - cat; if (cd < 0) cd = -cd;
                        if (cd <= 4) {
                            double ix1 = aX1[r] > x1 ? aX1[r] : x1;
                            double iy1 = aY1[r] > y1 ? aY1[r] : y1;
                            double ix2 = aX2[r] < x2 ? aX2[r] : x2;
                            double iy2 = aY2[r] < y2 ? aY2[r] : y2;
                            double iw = ix2 - ix1; if (iw < 0.0) iw = 0.0;
                            double ih = iy2 - iy1; if (ih < 0.0) ih = 0.0;
                            double inter = iw * ih;
                            double iou = inter / (aAR[r] + areaj - inter + 1e-9);
                            if (iou > 0.5) dead = true;
                        }
                    }
                    if (!dead && k > best) { best = k; bi = j; }  // j ascending: ties keep first index
                }
            }
            rvk[tid] = best; ri[tid] = bi;
            __syncthreads();
            for (int off = NTH / 2; off > 0; off >>= 1) {
                if (tid < off) {
                    if (rvk[tid + off] > rvk[tid] ||
                        (rvk[tid + off] == rvk[tid] && ri[tid + off] < ri[tid])) {
                        rvk[tid] = rvk[tid + off]; ri[tid] = ri[tid + off];
                    }
                }
                __syncthreads();
            }
            if (rvk[0] == 0u) break;
            if (tid == 0) {
                int j = ri[0];
                int cat = (int)CT[j];
                double bb[4];
                decode_box(b, j, rg0, rg1, rg2, rg3, rg4, anchors, bb);
                double shift = (double)cat * 1280.0;
                double x1 = bb[0] + shift, y1 = bb[1] + shift;
                double x2 = bb[2] + shift, y2 = bb[3] + shift;
                aX1[acc] = x1; aY1[acc] = y1; aX2[acc] = x2; aY2[acc] = y2;
                aAR[acc] = (x2 - x1) * (y2 - y1); aCT[acc] = cat;
                float* o = obuf + acc * 6;
                o[0] = (float)bb[0]; o[1] = (float)bb[1];
                o[2] = (float)bb[2]; o[3] = (float)bb[3];
                o[4] = (float)(1.0 / (1.0 + exp(-(double)__uint_as_float(rvk[0]))));
                o[5] = (float)cat;
                acc_s = acc + 1;
            }
            __syncthreads();
            acc = acc_s;
        }
    }
    __syncthreads();

    // ---- write output ---------------------------------------------------
    float* O = out + (size_t)b * NOUT * 6;
    for (int i = tid; i < NOUT * 6; i += NTH) O[i] = obuf[i];
}

extern "C" void kernel_launch(void* const* d_in, const int* in_sizes, int n_in,
                              void* d_out, int out_size, void* d_ws, size_t ws_size,
                              hipStream_t stream)
{
    // input dict order is interleaved: logits_i, regress_i pairs, anchors last
    const float* lg0 = (const float*)d_in[0];
    const float* rg0 = (const float*)d_in[1];
    const float* lg1 = (const float*)d_in[2];
    const float* rg1 = (const float*)d_in[3];
    const float* lg2 = (const float*)d_in[4];
    const float* rg2 = (const float*)d_in[5];
    const float* lg3 = (const float*)d_in[6];
    const float* rg3 = (const float*)d_in[7];
    const float* lg4 = (const float*)d_in[8];
    const float* rg4 = (const float*)d_in[9];
    const float* anchors = (const float*)d_in[10];

    char* ws = (char*)d_ws;
    unsigned*      keys   = (unsigned*)ws;                         // 8*A_PAD*4 = 2,455,296
    unsigned char* cats   = (unsigned char*)(ws + 2455296);        // 8*A_PAD   =   613,824
    unsigned*      hist   = (unsigned*)(ws + 3069184);             // 8*4096*4  =   131,072
    int*           ccount = (int*)(ws + 3200256);                  // 32 (contiguous after hist for one memset)
    int*           bstar  = (int*)(ws + 3200288);                  // 32
    int*           validc = (int*)(ws + 3200320);                  // 32
    unsigned long long* ckey = (unsigned long long*)(ws + 3200384);// 8*1024*8  =    65,536
    double*        cbox   = (double*)(ws + 3265920);               // 8*1024*32 =   262,144
    float*         cscore = (float*)(ws + 3528064);                // 8*1024*4  =    32,768

    hipMemsetAsync(hist, 0, 131072 + 32, stream);

    prep_kernel<<<dim3(NCHUNKS, NANCH, NBATCH), 512, 0, stream>>>(
        lg0, lg1, lg2, lg3, lg4, keys, cats, hist);

    select_kernel<<<NBATCH, NTH, 0, stream>>>(hist, bstar, validc);

    compact_kernel<<<dim3(NSLC, NBATCH), 256, 0, stream>>>(
        keys, cats, bstar, rg0, rg1, rg2, rg3, rg4, anchors,
        ckey, cbox, cscore, ccount);

    greedy_kernel<<<NBATCH, NTH, 0, stream>>>(
        keys, cats, rg0, rg1, rg2, rg3, rg4, anchors,
        ckey, cbox, cscore, ccount, validc, (float*)d_out);
}

// Round 9
// 387.264 us; speedup vs baseline: 1.0520x; 1.0158x over previous
//
#include <hip/hip_runtime.h>
#include <cmath>

#define A_TOT 76725
#define A_PAD 76728   // multiple of 4
#define NBATCH 8
#define NCLS 80
#define NANCH 9
#define NOUT 200

#define MCAP 1024     // compacted-candidate capacity (power of two, bitonic)
#define NTH 1024
#define NBUCK 4096
#define CHUNK 64
#define KBASE 0x3EC00000u   // f32 bits of 0.375 — below any passing key (>=~0.40547)
#define KSHIFT 16
#define NCHUNKS 36    // 25 (lvl0) + 7 (lvl1) + 2 (lvl2) + 1 (lvl3) + 1 (lvl4)
#define SCAP 8192            // per-batch staging capacity
#define STAGE_THR 3.25f      // staging threshold (logit); bits = 0x40500000
#define STAGE_BITS 0x40500000u

// ---------------------------------------------------------------------------
// f64 box decode, identical expressions to the verified rounds (absmax 0.0)
// — do not reorder these ops. Used by greedy's parallel decode (<=1024/batch)
// and by the fallbacks.
// ---------------------------------------------------------------------------
__device__ __forceinline__ void decode_box(int b, int j,
                                           const float* __restrict__ rg0,
                                           const float* __restrict__ rg1,
                                           const float* __restrict__ rg2,
                                           const float* __restrict__ rg3,
                                           const float* __restrict__ rg4,
                                           const float* __restrict__ anchors,
                                           double* __restrict__ o4)
{
    int s, base;
    const float* rg;
    if (j >= 76500)      { s = 25;   base = 76500; rg = rg4; }
    else if (j >= 75600) { s = 100;  base = 75600; rg = rg3; }
    else if (j >= 72000) { s = 400;  base = 72000; rg = rg2; }
    else if (j >= 57600) { s = 1600; base = 57600; rg = rg1; }
    else                 { s = 6400; base = 0;     rg = rg0; }
    const int rem = j - base;
    const int loc = rem / 9;
    const int aa  = rem - loc * 9;
    const size_t ro = ((size_t)(b * NANCH + aa) * 4) * s + loc;
    const float f0 = rg[ro];
    const float f1 = rg[ro + (size_t)s];
    const float f2 = rg[ro + 2 * (size_t)s];
    const float f3 = rg[ro + 3 * (size_t)s];

    double d0 = (double)f0, d1 = (double)f1, d2 = (double)f2, d3 = (double)f3;
    const float4 av = *(const float4*)(anchors + (size_t)j * 4);
    double ax1 = (double)av.x, ay1 = (double)av.y;
    double ax2 = (double)av.z, ay2 = (double)av.w;
    double aw = ax2 - ax1, ah = ay2 - ay1;
    double acx = ax1 + 0.5 * aw, acy = ay1 + 0.5 * ah;
    double cx = acx + d0 * aw, cy = acy + d1 * ah;
    double w = aw * exp(d2), h = ah * exp(d3);
    o4[0] = cx - 0.5 * w;
    o4[1] = cy - 0.5 * h;
    o4[2] = cx + 0.5 * w;
    o4[3] = cy + 0.5 * h;
}

// ---------------------------------------------------------------------------
// prep: R7/R8 structure + staging of high-key candidates (mv >= 3.25f):
// the packed u64 (keybits<<24 | 0xFFFFFF - (j<<7|cat)) is appended to a
// per-batch global staging buffer. 3.25 >> 0.406 so staging implies pass.
// Everything else byte-identical to R8.
// ---------------------------------------------------------------------------
#define CMP4(vv, cc)                                            \
    do {                                                        \
        if ((vv).x > m.x) { m.x = (vv).x; mcx = (cc); }         \
        if ((vv).y > m.y) { m.y = (vv).y; mcy = (cc); }         \
        if ((vv).z > m.z) { m.z = (vv).z; mcz = (cc); }         \
        if ((vv).w > m.w) { m.w = (vv).w; mcw = (cc); }         \
    } while (0)

__global__ __launch_bounds__(512, 4)
void prep_kernel(const float* __restrict__ lg0, const float* __restrict__ lg1,
                 const float* __restrict__ lg2, const float* __restrict__ lg3,
                 const float* __restrict__ lg4,
                 unsigned* __restrict__ keys,
                 unsigned char* __restrict__ cats,
                 unsigned* __restrict__ hist,
                 unsigned long long* __restrict__ stage,
                 int* __restrict__ scount)
{
    const int cx = blockIdx.x;
    const int a  = blockIdx.y;
    const int b  = blockIdx.z;
    int lvl, local;
    if (cx < 25)      { lvl = 0; local = cx; }
    else if (cx < 32) { lvl = 1; local = cx - 25; }
    else if (cx < 34) { lvl = 2; local = cx - 32; }
    else if (cx < 35) { lvl = 3; local = 0; }
    else              { lvl = 4; local = 0; }

    const int   sarr[5] = {6400, 1600, 400, 100, 25};
    const int   barr[5] = {0, 57600, 72000, 75600, 76500};
    const float* lgs[5] = {lg0, lg1, lg2, lg3, lg4};
    const int s = sarr[lvl], base = barr[lvl];
    const float* lg = lgs[lvl];

    __shared__ unsigned lh[NBUCK];       // 16 KB
    __shared__ float4   smv[7][64];      // 7 KB
    __shared__ int      smc[7][64][4];   // 7 KB

    const int tid = threadIdx.x;
    for (int i = tid; i < NBUCK; i += 512) lh[i] = 0u;

    const int t2 = tid & 63;            // 64 location-groups x 4 locs = 256 locs
    const int q  = tid >> 6;            // class slice 0..7 (10 classes each)
    const int c0 = q * 10;
    const int locbase = local * 256 + t2 * 4;
    const bool act = locbase < s;

    float mj[4]  = {-1e30f, -1e30f, -1e30f, -1e30f};
    int   mcj[4] = {0, 0, 0, 0};

    if (act) {
        const float* lga = lg + ((size_t)(b * NANCH + a) * NCLS) * s + locbase;
        if ((s & 3) == 0) {
            const float* p  = lga + (size_t)c0 * s;
            const size_t ss = (size_t)s;
            float4 v0 = *(const float4*)(p);
            float4 v1 = *(const float4*)(p + ss);
            float4 v2 = *(const float4*)(p + 2 * ss);
            float4 v3 = *(const float4*)(p + 3 * ss);
            float4 v4 = *(const float4*)(p + 4 * ss);
            float4 v5 = *(const float4*)(p + 5 * ss);
            float4 v6 = *(const float4*)(p + 6 * ss);
            float4 v7 = *(const float4*)(p + 7 * ss);
            float4 v8 = *(const float4*)(p + 8 * ss);
            float4 v9 = *(const float4*)(p + 9 * ss);
            float4 m = v0;
            int mcx = c0, mcy = c0, mcz = c0, mcw = c0;
            CMP4(v1, c0 + 1); CMP4(v2, c0 + 2); CMP4(v3, c0 + 3);
            CMP4(v4, c0 + 4); CMP4(v5, c0 + 5); CMP4(v6, c0 + 6);
            CMP4(v7, c0 + 7); CMP4(v8, c0 + 8); CMP4(v9, c0 + 9);
            mj[0] = m.x; mj[1] = m.y; mj[2] = m.z; mj[3] = m.w;
            mcj[0] = mcx; mcj[1] = mcy; mcj[2] = mcz; mcj[3] = mcw;
        } else {
            for (int j = 0; j < 4; ++j) {
                const int loc = locbase + j;
                if (loc >= s) break;
                const float* l1 = lga + j;
                float mv = l1[(size_t)c0 * s];
                int mc = c0;
                for (int c = c0 + 1; c < c0 + 10; ++c) {
                    float v1s = l1[(size_t)c * s];
                    if (v1s > mv) { mv = v1s; mc = c; }
                }
                mj[j] = mv; mcj[j] = mc;
            }
        }
    }

    if (q > 0 && act) {
        smv[q - 1][t2] = make_float4(mj[0], mj[1], mj[2], mj[3]);
        smc[q - 1][t2][0] = mcj[0]; smc[q - 1][t2][1] = mcj[1];
        smc[q - 1][t2][2] = mcj[2]; smc[q - 1][t2][3] = mcj[3];
    }
    __syncthreads();

    if (q == 0 && act) {
        #pragma unroll
        for (int h = 0; h < 7; ++h) {
            const float4 hv4 = smv[h][t2];
            const float* hv = (const float*)&hv4;
            #pragma unroll
            for (int j = 0; j < 4; ++j) {
                if (hv[j] > mj[j]) { mj[j] = hv[j]; mcj[j] = smc[h][t2][j]; }
            }
        }
        const size_t ob = (size_t)b * A_PAD + base + (size_t)locbase * NANCH + a;
        #pragma unroll
        for (int j = 0; j < 4; ++j) {
            const int loc = locbase + j;
            if (loc >= s) continue;
            const float mv = mj[j];
            bool pass;
            if (mv >= 0.406f)      pass = true;    // sigma >= 0.600128
            else if (mv < 0.405f)  pass = false;   // sigma <= 0.599889
            else pass = (1.0 / (1.0 + exp(-(double)mv)) >= 0.6);  // verbatim band
            unsigned kb = 0u;
            if (pass) {
                kb = __float_as_uint(mv);          // positive float -> bits order == value order
                unsigned bk = (kb - KBASE) >> KSHIFT;
                if (bk > NBUCK - 1) bk = NBUCK - 1;
                atomicAdd(&lh[bk], 1u);
                if (mv >= STAGE_THR) {
                    const unsigned aj = (unsigned)(base + (size_t)(locbase + j) * NANCH + a);
                    int p = atomicAdd(&scount[b], 1);
                    if (p < SCAP) {
                        stage[(size_t)b * SCAP + p] =
                            ((unsigned long long)kb << 24) |
                            (unsigned long long)(0xFFFFFFu - ((aj << 7) | (unsigned)mcj[j]));
                    }
                }
            }
            const size_t o = ob + (size_t)j * NANCH;
            keys[o] = kb;
            cats[o] = (unsigned char)mcj[j];
        }
    }
    __syncthreads();

    unsigned* H = hist + (size_t)b * NBUCK;
    for (int i = tid; i < NBUCK; i += 512) {
        unsigned v = lh[i];
        if (v) atomicAdd(&H[i], v);
    }
}

// ---------------------------------------------------------------------------
// greedy (select+compact fused, staged path): one block per batch.
// Phase 0: suffix-scan the FULL hist (complete — so bstar/valid are always
//   exact) in a reused LDS pool.
// Phase 1: gather candidates with bucket >= bstar. Trusted path: filter the
//   staged buffer (exact iff needed-set ⊆ staged-set, i.e. bucket_lower(bstar)
//   >= STAGE_BITS and no staging overflow). Otherwise: exact full-key scan.
// Phase 2: parallel f64 decode (verbatim) into cbox/cscore, 1 thread/cand.
// Phase 3: bitonic sort + chunk NMS + post-fallback — byte-identical to R8.
// ---------------------------------------------------------------------------
__launch_bounds__(NTH, 1)
__global__ void greedy_kernel(const unsigned* __restrict__ keys,
                              const unsigned char* __restrict__ cats,
                              const float* __restrict__ rg0, const float* __restrict__ rg1,
                              const float* __restrict__ rg2, const float* __restrict__ rg3,
                              const float* __restrict__ rg4,
                              const float* __restrict__ anchors,
                              const unsigned* __restrict__ hist,
                              const unsigned long long* __restrict__ stage,
                              const int* __restrict__ scount,
                              double* __restrict__ cbox,
                              float* __restrict__ cscore,
                              float* __restrict__ out)
{
    const int b = blockIdx.x;
    const int tid = threadIdx.x;

    __shared__ alignas(16) char pool[33280];
    __shared__ int bs_sh, valid_sh, cnt_sh, acc_s;

    const unsigned* K = keys + (size_t)b * A_PAD;
    const unsigned char* CT = cats + (size_t)b * A_PAD;

    // ---- phase 0: suffix scan of full hist (pool as sa/sb) -------------
    {
        unsigned* sa = (unsigned*)pool;             // 16384 B
        unsigned* sb = (unsigned*)(pool + 16384);   // 16384 B
        const unsigned* H = hist + (size_t)b * NBUCK;
        for (int i = tid; i < NBUCK; i += NTH) sa[i] = H[i];
        if (tid == 0) bs_sh = NBUCK;
        __syncthreads();
        unsigned* src = sa; unsigned* dst = sb;
        for (int off = 1; off < NBUCK; off <<= 1) {
            for (int i = tid; i < NBUCK; i += NTH)
                dst[i] = src[i] + ((i + off < NBUCK) ? src[i + off] : 0u);
            __syncthreads();
            unsigned* t = src; src = dst; dst = t;
        }
        for (int i = tid; i < NBUCK; i += NTH) {
            if (src[i] <= (unsigned)MCAP && (i == 0 || src[i - 1] > (unsigned)MCAP))
                bs_sh = i;
        }
        __syncthreads();
        if (tid == 0) { valid_sh = (int)src[0]; cnt_sh = 0; }
        __syncthreads();
    }
    const int bs = bs_sh;
    const int valid = valid_sh;

    // ---- re-carve pool for sort/NMS ------------------------------------
    unsigned long long* skey = (unsigned long long*)pool;   // 8192 B
    unsigned* sslot = (unsigned*)(pool + 8192);             // 4096 B
    char* ubuf = pool + 12288;                              // 20480 B

    // ---- phase 1: candidate gathering ----------------------------------
    {
        const unsigned Lb = KBASE + ((unsigned)bs << KSHIFT);  // bucket lower-bound bits
        const int S = scount[b];
        const bool trust = (S <= SCAP) && (Lb >= STAGE_BITS);
        if (trust) {
            for (int i = tid; i < S; i += NTH) {
                unsigned long long e = stage[(size_t)b * SCAP + i];
                if ((unsigned)(e >> 24) >= Lb) {
                    int p = atomicAdd(&cnt_sh, 1);
                    if (p < MCAP) skey[p] = e;
                }
            }
        } else {
            // exact fallback: full key scan (same rule as the old compact)
            for (int j = tid; j < A_TOT; j += NTH) {
                const unsigned k = K[j];
                if (k) {
                    int bk = (int)((k - KBASE) >> KSHIFT);
                    if (bk > NBUCK - 1) bk = NBUCK - 1;
                    if (bk >= bs) {
                        int p = atomicAdd(&cnt_sh, 1);
                        if (p < MCAP) {
                            unsigned pack = ((unsigned)j << 7) | (unsigned)CT[j];
                            skey[p] = ((unsigned long long)k << 24) |
                                      (unsigned long long)(0xFFFFFFu - pack);
                        }
                    }
                }
            }
        }
        __syncthreads();
    }
    const int cnt_raw = cnt_sh;
    const int cnt = cnt_raw < MCAP ? cnt_raw : MCAP;

    // ---- phase 2: pad + parallel decode (verbatim f64 expressions) -----
    for (int i = tid; i < MCAP; i += NTH) {
        if (i < cnt) {
            sslot[i] = (unsigned)i;
            unsigned long long e = skey[i];
            unsigned kb = (unsigned)(e >> 24);
            unsigned pack = 0xFFFFFFu - (unsigned)(e & 0xFFFFFFull);
            int j = (int)(pack >> 7);
            decode_box(b, j, rg0, rg1, rg2, rg3, rg4, anchors,
                       cbox + ((size_t)b * MCAP + i) * 4);
            double sgd = 1.0 / (1.0 + exp(-(double)__uint_as_float(kb)));
            cscore[(size_t)b * MCAP + i] = (float)sgd;
        } else {
            skey[i] = 0ull;
            sslot[i] = 0xFFFFFFFFu;
        }
    }
    __syncthreads();

    // ---- bitonic sort (combined key desc) ------------------------------
    for (int k = 2; k <= MCAP; k <<= 1) {
        for (int j2 = k >> 1; j2 > 0; j2 >>= 1) {
            for (int i = tid; i < MCAP; i += NTH) {
                int ixj = i ^ j2;
                if (ixj > i) {
                    unsigned long long ka = skey[i], kb2 = skey[ixj];
                    unsigned pa = sslot[i], pb = sslot[ixj];
                    bool before = (ka > kb2) || (ka == kb2 && pa < pb);
                    bool dir = ((i & k) == 0);
                    if (before != dir) {
                        skey[i] = kb2; skey[ixj] = ka;
                        sslot[i] = pb; sslot[ixj] = pa;
                    }
                }
            }
            __syncthreads();
        }
    }

    // ---- LDS layout for accepted/out/chunk (inside ubuf) ---------------
    double* aX1 = (double*)ubuf;                           // 200*8*5 = 8000
    double* aY1 = aX1 + NOUT;
    double* aX2 = aY1 + NOUT;
    double* aY2 = aX2 + NOUT;
    double* aAR = aY2 + NOUT;
    int*   aCT  = (int*)(ubuf + 8000);                     // 800
    float* obuf = (float*)(ubuf + 8800);                   // 4800
    double* cSX1 = (double*)(ubuf + 13600);                // 64*8 each
    double* cSY1 = (double*)(ubuf + 14112);
    double* cSX2 = (double*)(ubuf + 14624);
    double* cSY2 = (double*)(ubuf + 15136);
    double* cAR2 = (double*)(ubuf + 15648);
    double (*cUB)[4] = (double(*)[4])(ubuf + 16160);       // 64*32 = 2048
    int* cCat = (int*)(ubuf + 18208);                      // 256
    unsigned long long* cMask = (unsigned long long*)(ubuf + 18464);  // 512
    int* cSup = (int*)(ubuf + 18976);                      // 256
    float* cSc = (float*)(ubuf + 19232);                   // 256

    for (int i = tid; i < NOUT * 6; i += NTH)
        obuf[i] = ((i % 6) == 5) ? -1.0f : 0.0f;
    __syncthreads();

    // ---- chunk-parallel greedy sorted scan -----------------------------
    int acc = 0;
    for (int c0 = 0; c0 < cnt && acc < NOUT; c0 += CHUNK) {
        const int n = (cnt - c0) < CHUNK ? (cnt - c0) : CHUNK;

        if (tid < n) {
            unsigned long long ke = skey[c0 + tid];
            unsigned pack = 0xFFFFFFu - (unsigned)(ke & 0xFFFFFFull);
            int cat = (int)(pack & 127u);
            int sl = (int)sslot[c0 + tid];
            const double* bb = cbox + ((size_t)b * MCAP + sl) * 4;
            double b0 = bb[0], b1 = bb[1], b2 = bb[2], b3 = bb[3];
            cUB[tid][0] = b0; cUB[tid][1] = b1; cUB[tid][2] = b2; cUB[tid][3] = b3;
            double shift = (double)cat * 1280.0;
            double x1 = b0 + shift, y1 = b1 + shift;
            double x2 = b2 + shift, y2 = b3 + shift;
            cSX1[tid] = x1; cSY1[tid] = y1; cSX2[tid] = x2; cSY2[tid] = y2;
            cAR2[tid] = (x2 - x1) * (y2 - y1);
            cCat[tid] = cat;
            cSc[tid] = cscore[(size_t)b * MCAP + sl];
            cMask[tid] = 0ull;
            cSup[tid] = 0;
        }
        __syncthreads();

        // (a) candidates vs accepted list: 16 threads per candidate
        {
            const int i = tid >> 4;
            if (i < n) {
                const int cat = cCat[i];
                const double x1 = cSX1[i], y1 = cSY1[i];
                const double x2 = cSX2[i], y2 = cSY2[i];
                const double areaj = cAR2[i];
                bool f = false;
                for (int r = (tid & 15); r < acc; r += 16) {
                    int cd = aCT[r] - cat; if (cd < 0) cd = -cd;
                    if (cd <= 4) {
                        double ix1 = aX1[r] > x1 ? aX1[r] : x1;
                        double iy1 = aY1[r] > y1 ? aY1[r] : y1;
                        double ix2 = aX2[r] < x2 ? aX2[r] : x2;
                        double iy2 = aY2[r] < y2 ? aY2[r] : y2;
                        double iw = ix2 - ix1; if (iw < 0.0) iw = 0.0;
                        double ih = iy2 - iy1; if (ih < 0.0) ih = 0.0;
                        double inter = iw * ih;
                        double iou = inter / (aAR[r] + areaj - inter + 1e-9);
                        if (iou > 0.5) f = true;
                    }
                }
                if (f) cSup[i] = 1;
            }
        }

        // (b) intra-chunk 64x64 suppression mask (j < i; j as would-be pick)
        for (int p = tid; p < (n << 6); p += NTH) {
            const int i = p >> 6, j = p & 63;
            if (j < i && j < n) {
                int cd = cCat[j] - cCat[i]; if (cd < 0) cd = -cd;
                if (cd <= 4) {
                    double x1 = cSX1[i], y1 = cSY1[i];
                    double x2 = cSX2[i], y2 = cSY2[i];
                    double ix1 = cSX1[j] > x1 ? cSX1[j] : x1;
                    double iy1 = cSY1[j] > y1 ? cSY1[j] : y1;
                    double ix2 = cSX2[j] < x2 ? cSX2[j] : x2;
                    double iy2 = cSY2[j] < y2 ? cSY2[j] : y2;
                    double iw = ix2 - ix1; if (iw < 0.0) iw = 0.0;
                    double ih = iy2 - iy1; if (ih < 0.0) ih = 0.0;
                    double inter = iw * ih;
                    double iou = inter / (cAR2[j] + cAR2[i] - inter + 1e-9);
                    if (iou > 0.5)
                        atomicOr(&cMask[i], 1ull << j);
                }
            }
        }
        __syncthreads();

        // (c) wave-parallel alive-mask walk (first wave only).
        if (tid < 64) {
            const int lane = tid;
            unsigned long long m = 0ull;
            int supv = 1;
            if (lane < n) { m = cMask[lane]; supv = cSup[lane]; }
            unsigned long long alive = __ballot(lane < n && !supv);
            unsigned long long am = 0ull;
            int a2 = acc;
            while (alive && a2 < NOUT) {
                int i = (int)__ffsll((unsigned long long)alive) - 1;
                am |= 1ull << i;
                ++a2;
                unsigned long long kill = __ballot((m >> i) & 1ull);
                alive &= ~(kill | (1ull << i));
            }
            if (am & (1ull << lane)) {
                int pos = acc + (int)__popcll(am & ((1ull << lane) - 1ull));
                aX1[pos] = cSX1[lane]; aY1[pos] = cSY1[lane];
                aX2[pos] = cSX2[lane]; aY2[pos] = cSY2[lane];
                aAR[pos] = cAR2[lane]; aCT[pos] = cCat[lane];
                float* o = obuf + pos * 6;
                o[0] = (float)cUB[lane][0]; o[1] = (float)cUB[lane][1];
                o[2] = (float)cUB[lane][2]; o[3] = (float)cUB[lane][3];
                o[4] = cSc[lane];
                o[5] = (float)cCat[lane];
            }
            if (lane == 0) acc_s = acc + (int)__popcll(am);
        }
        __syncthreads();
        acc = acc_s;
    }

    // ---- exact fallback (pathological only) ----------------------------
    if (acc < NOUT && cnt < valid) {
        unsigned* rvk = (unsigned*)skey;
        int*      ri  = (int*)sslot;
        while (acc < NOUT) {
            unsigned best = 0u;
            int bi = 0x7fffffff;
            for (int j = tid; j < A_TOT; j += NTH) {
                const unsigned k = K[j];
                if (k) {
                    int cat = (int)CT[j];
                    double bb[4];
                    decode_box(b, j, rg0, rg1, rg2, rg3, rg4, anchors, bb);
                    double shift = (double)cat * 1280.0;
                    double x1 = bb[0] + shift, y1 = bb[1] + shift;
                    double x2 = bb[2] + shift, y2 = bb[3] + shift;
                    double areaj = (x2 - x1) * (y2 - y1);
                    bool dead = false;
                    for (int r = 0; r < acc && !dead; ++r) {
                        int cd = aCT[r] - cat; if (cd < 0) cd = -cd;
                        if (cd <= 4) {
                            double ix1 = aX1[r] > x1 ? aX1[r] : x1;
                            double iy1 = aY1[r] > y1 ? aY1[r] : y1;
                            double ix2 = aX2[r] < x2 ? aX2[r] : x2;
                            double iy2 = aY2[r] < y2 ? aY2[r] : y2;
                            double iw = ix2 - ix1; if (iw < 0.0) iw = 0.0;
                            double ih = iy2 - iy1; if (ih < 0.0) ih = 0.0;
                            double inter = iw * ih;
                            double iou = inter / (aAR[r] + areaj - inter + 1e-9);
                            if (iou > 0.5) dead = true;
                        }
                    }
                    if (!dead && k > best) { best = k; bi = j; }  // j ascending: ties keep first index
                }
            }
            rvk[tid] = best; ri[tid] = bi;
            __syncthreads();
            for (int off = NTH / 2; off > 0; off >>= 1) {
                if (tid < off) {
                    if (rvk[tid + off] > rvk[tid] ||
                        (rvk[tid + off] == rvk[tid] && ri[tid + off] < ri[tid])) {
                        rvk[tid] = rvk[tid + off]; ri[tid] = ri[tid + off];
                    }
                }
                __syncthreads();
            }
            if (rvk[0] == 0u) break;
            if (tid == 0) {
                int j = ri[0];
                int cat = (int)CT[j];
                double bb[4];
                decode_box(b, j, rg0, rg1, rg2, rg3, rg4, anchors, bb);
                double shift = (double)cat * 1280.0;
                double x1 = bb[0] + shift, y1 = bb[1] + shift;
                double x2 = bb[2] + shift, y2 = bb[3] + shift;
                aX1[acc] = x1; aY1[acc] = y1; aX2[acc] = x2; aY2[acc] = y2;
                aAR[acc] = (x2 - x1) * (y2 - y1); aCT[acc] = cat;
                float* o = obuf + acc * 6;
                o[0] = (float)bb[0]; o[1] = (float)bb[1];
                o[2] = (float)bb[2]; o[3] = (float)bb[3];
                o[4] = (float)(1.0 / (1.0 + exp(-(double)__uint_as_float(rvk[0]))));
                o[5] = (float)cat;
                acc_s = acc + 1;
            }
            __syncthreads();
            acc = acc_s;
        }
    }
    __syncthreads();

    // ---- write output ---------------------------------------------------
    float* O = out + (size_t)b * NOUT * 6;
    for (int i = tid; i < NOUT * 6; i += NTH) O[i] = obuf[i];
}

extern "C" void kernel_launch(void* const* d_in, const int* in_sizes, int n_in,
                              void* d_out, int out_size, void* d_ws, size_t ws_size,
                              hipStream_t stream)
{
    // input dict order is interleaved: logits_i, regress_i pairs, anchors last
    const float* lg0 = (const float*)d_in[0];
    const float* rg0 = (const float*)d_in[1];
    const float* lg1 = (const float*)d_in[2];
    const float* rg1 = (const float*)d_in[3];
    const float* lg2 = (const float*)d_in[4];
    const float* rg2 = (const float*)d_in[5];
    const float* lg3 = (const float*)d_in[6];
    const float* rg3 = (const float*)d_in[7];
    const float* lg4 = (const float*)d_in[8];
    const float* rg4 = (const float*)d_in[9];
    const float* anchors = (const float*)d_in[10];

    char* ws = (char*)d_ws;
    unsigned*      keys   = (unsigned*)ws;                          // 2,455,296
    unsigned char* cats   = (unsigned char*)(ws + 2455296);         //   613,824
    unsigned*      hist   = (unsigned*)(ws + 3069184);              //   131,072
    int*           scount = (int*)(ws + 3200256);                   //        32 (contiguous after hist)
    unsigned long long* stage = (unsigned long long*)(ws + 3200512);// 8*8192*8 = 524,288
    double*        cbox   = (double*)(ws + 3724800);                // 8*1024*32 = 262,144
    float*         cscore = (float*)(ws + 3986944);                 // 8*1024*4  =  32,768

    hipMemsetAsync(hist, 0, 131072 + 32, stream);

    prep_kernel<<<dim3(NCHUNKS, NANCH, NBATCH), 512, 0, stream>>>(
        lg0, lg1, lg2, lg3, lg4, keys, cats, hist, stage, scount);

    greedy_kernel<<<NBATCH, NTH, 0, stream>>>(
        keys, cats, rg0, rg1, rg2, rg3, rg4, anchors,
        hist, stage, scount, cbox, cscore, (float*)d_out);
}

// Round 10
// 342.220 us; speedup vs baseline: 1.1904x; 1.1316x over previous
//
#include <hip/hip_runtime.h>
#include <cmath>

#define A_TOT 76725
#define A_PAD 76728   // multiple of 4
#define NBATCH 8
#define NCLS 80
#define NANCH 9
#define NOUT 200

#define MCAP 1024     // compacted-candidate capacity (power of two, bitonic)
#define NTH 1024
#define NBUCK 4096
#define CHUNK 64
#define KBASE 0x3EC00000u   // f32 bits of 0.375 — below any passing key (>=~0.40547)
#define KSHIFT 16
#define NCHUNKS 36    // 25 (lvl0) + 7 (lvl1) + 2 (lvl2) + 1 (lvl3) + 1 (lvl4)
#define SCAP 8192            // per-batch staging capacity
#define STAGE_THR 3.25f      // staging threshold (logit); bits = 0x40500000
#define STAGE_BITS 0x40500000u
#define SCSTRIDE 64          // scount padding: 64 ints = 256 B per batch

// ---------------------------------------------------------------------------
// f64 box decode, identical expressions to the verified rounds (absmax 0.0)
// — do not reorder these ops. Used by greedy's parallel decode (<=1024/batch)
// and by the fallbacks.
// ---------------------------------------------------------------------------
__device__ __forceinline__ void decode_box(int b, int j,
                                           const float* __restrict__ rg0,
                                           const float* __restrict__ rg1,
                                           const float* __restrict__ rg2,
                                           const float* __restrict__ rg3,
                                           const float* __restrict__ rg4,
                                           const float* __restrict__ anchors,
                                           double* __restrict__ o4)
{
    int s, base;
    const float* rg;
    if (j >= 76500)      { s = 25;   base = 76500; rg = rg4; }
    else if (j >= 75600) { s = 100;  base = 75600; rg = rg3; }
    else if (j >= 72000) { s = 400;  base = 72000; rg = rg2; }
    else if (j >= 57600) { s = 1600; base = 57600; rg = rg1; }
    else                 { s = 6400; base = 0;     rg = rg0; }
    const int rem = j - base;
    const int loc = rem / 9;
    const int aa  = rem - loc * 9;
    const size_t ro = ((size_t)(b * NANCH + aa) * 4) * s + loc;
    const float f0 = rg[ro];
    const float f1 = rg[ro + (size_t)s];
    const float f2 = rg[ro + 2 * (size_t)s];
    const float f3 = rg[ro + 3 * (size_t)s];

    double d0 = (double)f0, d1 = (double)f1, d2 = (double)f2, d3 = (double)f3;
    const float4 av = *(const float4*)(anchors + (size_t)j * 4);
    double ax1 = (double)av.x, ay1 = (double)av.y;
    double ax2 = (double)av.z, ay2 = (double)av.w;
    double aw = ax2 - ax1, ah = ay2 - ay1;
    double acx = ax1 + 0.5 * aw, acy = ay1 + 0.5 * ah;
    double cx = acx + d0 * aw, cy = acy + d1 * ah;
    double w = aw * exp(d2), h = ah * exp(d3);
    o4[0] = cx - 0.5 * w;
    o4[1] = cy - 0.5 * h;
    o4[2] = cx + 0.5 * w;
    o4[3] = cy + 0.5 * h;
}

// ---------------------------------------------------------------------------
// prep: R8 structure + TWO-LEVEL staging (mv >= 3.25f): entries collected in
// an LDS buffer with LDS atomics (per-block max = 4*256 = 1024 entries,
// lstage never overflows), then ONE global atomicAdd per block reserves a
// contiguous range in the per-batch stage buffer (scount padded to 256 B per
// batch — no false sharing). R9's per-item device-scope atomics on packed
// counters serialized cross-XCD and cost prep +40 us.
// Everything else byte-identical to R8/R9.
// ---------------------------------------------------------------------------
#define CMP4(vv, cc)                                            \
    do {                                                        \
        if ((vv).x > m.x) { m.x = (vv).x; mcx = (cc); }         \
        if ((vv).y > m.y) { m.y = (vv).y; mcy = (cc); }         \
        if ((vv).z > m.z) { m.z = (vv).z; mcz = (cc); }         \
        if ((vv).w > m.w) { m.w = (vv).w; mcw = (cc); }         \
    } while (0)

__global__ __launch_bounds__(512, 4)
void prep_kernel(const float* __restrict__ lg0, const float* __restrict__ lg1,
                 const float* __restrict__ lg2, const float* __restrict__ lg3,
                 const float* __restrict__ lg4,
                 unsigned* __restrict__ keys,
                 unsigned char* __restrict__ cats,
                 unsigned* __restrict__ hist,
                 unsigned long long* __restrict__ stage,
                 int* __restrict__ scount)
{
    const int cx = blockIdx.x;
    const int a  = blockIdx.y;
    const int b  = blockIdx.z;
    int lvl, local;
    if (cx < 25)      { lvl = 0; local = cx; }
    else if (cx < 32) { lvl = 1; local = cx - 25; }
    else if (cx < 34) { lvl = 2; local = cx - 32; }
    else if (cx < 35) { lvl = 3; local = 0; }
    else              { lvl = 4; local = 0; }

    const int   sarr[5] = {6400, 1600, 400, 100, 25};
    const int   barr[5] = {0, 57600, 72000, 75600, 76500};
    const float* lgs[5] = {lg0, lg1, lg2, lg3, lg4};
    const int s = sarr[lvl], base = barr[lvl];
    const float* lg = lgs[lvl];

    __shared__ unsigned lh[NBUCK];             // 16 KB
    __shared__ float4   smv[7][64];            // 7 KB
    __shared__ int      smc[7][64][4];         // 7 KB
    __shared__ unsigned long long lstage[1024];// 8 KB (max 4*256 entries)
    __shared__ int lsc, sbase;

    const int tid = threadIdx.x;
    for (int i = tid; i < NBUCK; i += 512) lh[i] = 0u;
    if (tid == 0) lsc = 0;

    const int t2 = tid & 63;            // 64 location-groups x 4 locs = 256 locs
    const int q  = tid >> 6;            // class slice 0..7 (10 classes each)
    const int c0 = q * 10;
    const int locbase = local * 256 + t2 * 4;
    const bool act = locbase < s;

    float mj[4]  = {-1e30f, -1e30f, -1e30f, -1e30f};
    int   mcj[4] = {0, 0, 0, 0};

    if (act) {
        const float* lga = lg + ((size_t)(b * NANCH + a) * NCLS) * s + locbase;
        if ((s & 3) == 0) {
            const float* p  = lga + (size_t)c0 * s;
            const size_t ss = (size_t)s;
            float4 v0 = *(const float4*)(p);
            float4 v1 = *(const float4*)(p + ss);
            float4 v2 = *(const float4*)(p + 2 * ss);
            float4 v3 = *(const float4*)(p + 3 * ss);
            float4 v4 = *(const float4*)(p + 4 * ss);
            float4 v5 = *(const float4*)(p + 5 * ss);
            float4 v6 = *(const float4*)(p + 6 * ss);
            float4 v7 = *(const float4*)(p + 7 * ss);
            float4 v8 = *(const float4*)(p + 8 * ss);
            float4 v9 = *(const float4*)(p + 9 * ss);
            float4 m = v0;
            int mcx = c0, mcy = c0, mcz = c0, mcw = c0;
            CMP4(v1, c0 + 1); CMP4(v2, c0 + 2); CMP4(v3, c0 + 3);
            CMP4(v4, c0 + 4); CMP4(v5, c0 + 5); CMP4(v6, c0 + 6);
            CMP4(v7, c0 + 7); CMP4(v8, c0 + 8); CMP4(v9, c0 + 9);
            mj[0] = m.x; mj[1] = m.y; mj[2] = m.z; mj[3] = m.w;
            mcj[0] = mcx; mcj[1] = mcy; mcj[2] = mcz; mcj[3] = mcw;
        } else {
            for (int j = 0; j < 4; ++j) {
                const int loc = locbase + j;
                if (loc >= s) break;
                const float* l1 = lga + j;
                float mv = l1[(size_t)c0 * s];
                int mc = c0;
                for (int c = c0 + 1; c < c0 + 10; ++c) {
                    float v1s = l1[(size_t)c * s];
                    if (v1s > mv) { mv = v1s; mc = c; }
                }
                mj[j] = mv; mcj[j] = mc;
            }
        }
    }

    if (q > 0 && act) {
        smv[q - 1][t2] = make_float4(mj[0], mj[1], mj[2], mj[3]);
        smc[q - 1][t2][0] = mcj[0]; smc[q - 1][t2][1] = mcj[1];
        smc[q - 1][t2][2] = mcj[2]; smc[q - 1][t2][3] = mcj[3];
    }
    __syncthreads();

    if (q == 0 && act) {
        #pragma unroll
        for (int h = 0; h < 7; ++h) {
            const float4 hv4 = smv[h][t2];
            const float* hv = (const float*)&hv4;
            #pragma unroll
            for (int j = 0; j < 4; ++j) {
                if (hv[j] > mj[j]) { mj[j] = hv[j]; mcj[j] = smc[h][t2][j]; }
            }
        }
        const size_t ob = (size_t)b * A_PAD + base + (size_t)locbase * NANCH + a;
        #pragma unroll
        for (int j = 0; j < 4; ++j) {
            const int loc = locbase + j;
            if (loc >= s) continue;
            const float mv = mj[j];
            bool pass;
            if (mv >= 0.406f)      pass = true;    // sigma >= 0.600128
            else if (mv < 0.405f)  pass = false;   // sigma <= 0.599889
            else pass = (1.0 / (1.0 + exp(-(double)mv)) >= 0.6);  // verbatim band
            unsigned kb = 0u;
            if (pass) {
                kb = __float_as_uint(mv);          // positive float -> bits order == value order
                unsigned bk = (kb - KBASE) >> KSHIFT;
                if (bk > NBUCK - 1) bk = NBUCK - 1;
                atomicAdd(&lh[bk], 1u);
                if (mv >= STAGE_THR) {
                    const unsigned aj = (unsigned)(base + (size_t)(locbase + j) * NANCH + a);
                    int p = atomicAdd(&lsc, 1);    // LDS atomic; p < 1024 guaranteed
                    lstage[p] =
                        ((unsigned long long)kb << 24) |
                        (unsigned long long)(0xFFFFFFu - ((aj << 7) | (unsigned)mcj[j]));
                }
            }
            const size_t o = ob + (size_t)j * NANCH;
            keys[o] = kb;
            cats[o] = (unsigned char)mcj[j];
        }
    }
    __syncthreads();

    unsigned* H = hist + (size_t)b * NBUCK;
    for (int i = tid; i < NBUCK; i += 512) {
        unsigned v = lh[i];
        if (v) atomicAdd(&H[i], v);
    }

    // ---- staging flush: ONE global atomic per block --------------------
    const int nl = lsc;
    if (nl > 0) {
        if (tid == 0) sbase = atomicAdd(&scount[b * SCSTRIDE], nl);
        __syncthreads();
        const int bse = sbase;
        for (int i = tid; i < nl; i += 512) {
            const int d = bse + i;
            if (d < SCAP) stage[(size_t)b * SCAP + d] = lstage[i];
        }
    }
}

// ---------------------------------------------------------------------------
// greedy (select+compact fused, staged path): one block per batch.
// Phase 0: suffix-scan the FULL hist (complete — so bstar/valid are always
//   exact) in a reused LDS pool.
// Phase 1: gather candidates with bucket >= bstar. Trusted path: filter the
//   staged buffer (exact iff needed-set ⊆ staged-set, i.e. bucket_lower(bstar)
//   >= STAGE_BITS and no staging overflow). Otherwise: exact full-key scan.
// Phase 2: parallel f64 decode (verbatim) into cbox/cscore, 1 thread/cand.
// Phase 3: bitonic sort + chunk NMS + post-fallback — byte-identical to R8.
// ---------------------------------------------------------------------------
__launch_bounds__(NTH, 1)
__global__ void greedy_kernel(const unsigned* __restrict__ keys,
                              const unsigned char* __restrict__ cats,
                              const float* __restrict__ rg0, const float* __restrict__ rg1,
                              const float* __restrict__ rg2, const float* __restrict__ rg3,
                              const float* __restrict__ rg4,
                              const float* __restrict__ anchors,
                              const unsigned* __restrict__ hist,
                              const unsigned long long* __restrict__ stage,
                              const int* __restrict__ scount,
                              double* __restrict__ cbox,
                              float* __restrict__ cscore,
                              float* __restrict__ out)
{
    const int b = blockIdx.x;
    const int tid = threadIdx.x;

    __shared__ alignas(16) char pool[33280];
    __shared__ int bs_sh, valid_sh, cnt_sh, acc_s;

    const unsigned* K = keys + (size_t)b * A_PAD;
    const unsigned char* CT = cats + (size_t)b * A_PAD;

    // ---- phase 0: suffix scan of full hist (pool as sa/sb) -------------
    {
        unsigned* sa = (unsigned*)pool;             // 16384 B
        unsigned* sb = (unsigned*)(pool + 16384);   // 16384 B
        const unsigned* H = hist + (size_t)b * NBUCK;
        for (int i = tid; i < NBUCK; i += NTH) sa[i] = H[i];
        if (tid == 0) bs_sh = NBUCK;
        __syncthreads();
        unsigned* src = sa; unsigned* dst = sb;
        for (int off = 1; off < NBUCK; off <<= 1) {
            for (int i = tid; i < NBUCK; i += NTH)
                dst[i] = src[i] + ((i + off < NBUCK) ? src[i + off] : 0u);
            __syncthreads();
            unsigned* t = src; src = dst; dst = t;
        }
        for (int i = tid; i < NBUCK; i += NTH) {
            if (src[i] <= (unsigned)MCAP && (i == 0 || src[i - 1] > (unsigned)MCAP))
                bs_sh = i;
        }
        __syncthreads();
        if (tid == 0) { valid_sh = (int)src[0]; cnt_sh = 0; }
        __syncthreads();
    }
    const int bs = bs_sh;
    const int valid = valid_sh;

    // ---- re-carve pool for sort/NMS ------------------------------------
    unsigned long long* skey = (unsigned long long*)pool;   // 8192 B
    unsigned* sslot = (unsigned*)(pool + 8192);             // 4096 B
    char* ubuf = pool + 12288;                              // 20480 B

    // ---- phase 1: candidate gathering ----------------------------------
    {
        const unsigned Lb = KBASE + ((unsigned)bs << KSHIFT);  // bucket lower-bound bits
        const int S = scount[b * SCSTRIDE];
        const bool trust = (S <= SCAP) && (Lb >= STAGE_BITS);
        if (trust) {
            for (int i = tid; i < S; i += NTH) {
                unsigned long long e = stage[(size_t)b * SCAP + i];
                if ((unsigned)(e >> 24) >= Lb) {
                    int p = atomicAdd(&cnt_sh, 1);
                    if (p < MCAP) skey[p] = e;
                }
            }
        } else {
            // exact fallback: full key scan (same rule as the old compact)
            for (int j = tid; j < A_TOT; j += NTH) {
                const unsigned k = K[j];
                if (k) {
                    int bk = (int)((k - KBASE) >> KSHIFT);
                    if (bk > NBUCK - 1) bk = NBUCK - 1;
                    if (bk >= bs) {
                        int p = atomicAdd(&cnt_sh, 1);
                        if (p < MCAP) {
                            unsigned pack = ((unsigned)j << 7) | (unsigned)CT[j];
                            skey[p] = ((unsigned long long)k << 24) |
                                      (unsigned long long)(0xFFFFFFu - pack);
                        }
                    }
                }
            }
        }
        __syncthreads();
    }
    const int cnt_raw = cnt_sh;
    const int cnt = cnt_raw < MCAP ? cnt_raw : MCAP;

    // ---- phase 2: pad + parallel decode (verbatim f64 expressions) -----
    for (int i = tid; i < MCAP; i += NTH) {
        if (i < cnt) {
            sslot[i] = (unsigned)i;
            unsigned long long e = skey[i];
            unsigned kb = (unsigned)(e >> 24);
            unsigned pack = 0xFFFFFFu - (unsigned)(e & 0xFFFFFFull);
            int j = (int)(pack >> 7);
            decode_box(b, j, rg0, rg1, rg2, rg3, rg4, anchors,
                       cbox + ((size_t)b * MCAP + i) * 4);
            double sgd = 1.0 / (1.0 + exp(-(double)__uint_as_float(kb)));
            cscore[(size_t)b * MCAP + i] = (float)sgd;
        } else {
            skey[i] = 0ull;
            sslot[i] = 0xFFFFFFFFu;
        }
    }
    __syncthreads();

    // ---- bitonic sort (combined key desc) ------------------------------
    for (int k = 2; k <= MCAP; k <<= 1) {
        for (int j2 = k >> 1; j2 > 0; j2 >>= 1) {
            for (int i = tid; i < MCAP; i += NTH) {
                int ixj = i ^ j2;
                if (ixj > i) {
                    unsigned long long ka = skey[i], kb2 = skey[ixj];
                    unsigned pa = sslot[i], pb = sslot[ixj];
                    bool before = (ka > kb2) || (ka == kb2 && pa < pb);
                    bool dir = ((i & k) == 0);
                    if (before != dir) {
                        skey[i] = kb2; skey[ixj] = ka;
                        sslot[i] = pb; sslot[ixj] = pa;
                    }
                }
            }
            __syncthreads();
        }
    }

    // ---- LDS layout for accepted/out/chunk (inside ubuf) ---------------
    double* aX1 = (double*)ubuf;                           // 200*8*5 = 8000
    double* aY1 = aX1 + NOUT;
    double* aX2 = aY1 + NOUT;
    double* aY2 = aX2 + NOUT;
    double* aAR = aY2 + NOUT;
    int*   aCT  = (int*)(ubuf + 8000);                     // 800
    float* obuf = (float*)(ubuf + 8800);                   // 4800
    double* cSX1 = (double*)(ubuf + 13600);                // 64*8 each
    double* cSY1 = (double*)(ubuf + 14112);
    double* cSX2 = (double*)(ubuf + 14624);
    double* cSY2 = (double*)(ubuf + 15136);
    double* cAR2 = (double*)(ubuf + 15648);
    double (*cUB)[4] = (double(*)[4])(ubuf + 16160);       // 64*32 = 2048
    int* cCat = (int*)(ubuf + 18208);                      // 256
    unsigned long long* cMask = (unsigned long long*)(ubuf + 18464);  // 512
    int* cSup = (int*)(ubuf + 18976);                      // 256
    float* cSc = (float*)(ubuf + 19232);                   // 256

    for (int i = tid; i < NOUT * 6; i += NTH)
        obuf[i] = ((i % 6) == 5) ? -1.0f : 0.0f;
    __syncthreads();

    // ---- chunk-parallel greedy sorted scan -----------------------------
    int acc = 0;
    for (int c0 = 0; c0 < cnt && acc < NOUT; c0 += CHUNK) {
        const int n = (cnt - c0) < CHUNK ? (cnt - c0) : CHUNK;

        if (tid < n) {
            unsigned long long ke = skey[c0 + tid];
            unsigned pack = 0xFFFFFFu - (unsigned)(ke & 0xFFFFFFull);
            int cat = (int)(pack & 127u);
            int sl = (int)sslot[c0 + tid];
            const double* bb = cbox + ((size_t)b * MCAP + sl) * 4;
            double b0 = bb[0], b1 = bb[1], b2 = bb[2], b3 = bb[3];
            cUB[tid][0] = b0; cUB[tid][1] = b1; cUB[tid][2] = b2; cUB[tid][3] = b3;
            double shift = (double)cat * 1280.0;
            double x1 = b0 + shift, y1 = b1 + shift;
            double x2 = b2 + shift, y2 = b3 + shift;
            cSX1[tid] = x1; cSY1[tid] = y1; cSX2[tid] = x2; cSY2[tid] = y2;
            cAR2[tid] = (x2 - x1) * (y2 - y1);
            cCat[tid] = cat;
            cSc[tid] = cscore[(size_t)b * MCAP + sl];
            cMask[tid] = 0ull;
            cSup[tid] = 0;
        }
        __syncthreads();

        // (a) candidates vs accepted list: 16 threads per candidate
        {
            const int i = tid >> 4;
            if (i < n) {
                const int cat = cCat[i];
                const double x1 = cSX1[i], y1 = cSY1[i];
                const double x2 = cSX2[i], y2 = cSY2[i];
                const double areaj = cAR2[i];
                bool f = false;
                for (int r = (tid & 15); r < acc; r += 16) {
                    int cd = aCT[r] - cat; if (cd < 0) cd = -cd;
                    if (cd <= 4) {
                        double ix1 = aX1[r] > x1 ? aX1[r] : x1;
                        double iy1 = aY1[r] > y1 ? aY1[r] : y1;
                        double ix2 = aX2[r] < x2 ? aX2[r] : x2;
                        double iy2 = aY2[r] < y2 ? aY2[r] : y2;
                        double iw = ix2 - ix1; if (iw < 0.0) iw = 0.0;
                        double ih = iy2 - iy1; if (ih < 0.0) ih = 0.0;
                        double inter = iw * ih;
                        double iou = inter / (aAR[r] + areaj - inter + 1e-9);
                        if (iou > 0.5) f = true;
                    }
                }
                if (f) cSup[i] = 1;
            }
        }

        // (b) intra-chunk 64x64 suppression mask (j < i; j as would-be pick)
        for (int p = tid; p < (n << 6); p += NTH) {
            const int i = p >> 6, j = p & 63;
            if (j < i && j < n) {
                int cd = cCat[j] - cCat[i]; if (cd < 0) cd = -cd;
                if (cd <= 4) {
                    double x1 = cSX1[i], y1 = cSY1[i];
                    double x2 = cSX2[i], y2 = cSY2[i];
                    double ix1 = cSX1[j] > x1 ? cSX1[j] : x1;
                    double iy1 = cSY1[j] > y1 ? cSY1[j] : y1;
                    double ix2 = cSX2[j] < x2 ? cSX2[j] : x2;
                    double iy2 = cSY2[j] < y2 ? cSY2[j] : y2;
                    double iw = ix2 - ix1; if (iw < 0.0) iw = 0.0;
                    double ih = iy2 - iy1; if (ih < 0.0) ih = 0.0;
                    double inter = iw * ih;
                    double iou = inter / (cAR2[j] + cAR2[i] - inter + 1e-9);
                    if (iou > 0.5)
                        atomicOr(&cMask[i], 1ull << j);
                }
            }
        }
        __syncthreads();

        // (c) wave-parallel alive-mask walk (first wave only).
        if (tid < 64) {
            const int lane = tid;
            unsigned long long m = 0ull;
            int supv = 1;
            if (lane < n) { m = cMask[lane]; supv = cSup[lane]; }
            unsigned long long alive = __ballot(lane < n && !supv);
            unsigned long long am = 0ull;
            int a2 = acc;
            while (alive && a2 < NOUT) {
                int i = (int)__ffsll((unsigned long long)alive) - 1;
                am |= 1ull << i;
                ++a2;
                unsigned long long kill = __ballot((m >> i) & 1ull);
                alive &= ~(kill | (1ull << i));
            }
            if (am & (1ull << lane)) {
                int pos = acc + (int)__popcll(am & ((1ull << lane) - 1ull));
                aX1[pos] = cSX1[lane]; aY1[pos] = cSY1[lane];
                aX2[pos] = cSX2[lane]; aY2[pos] = cSY2[lane];
                aAR[pos] = cAR2[lane]; aCT[pos] = cCat[lane];
                float* o = obuf + pos * 6;
                o[0] = (float)cUB[lane][0]; o[1] = (float)cUB[lane][1];
                o[2] = (float)cUB[lane][2]; o[3] = (float)cUB[lane][3];
                o[4] = cSc[lane];
                o[5] = (float)cCat[lane];
            }
            if (lane == 0) acc_s = acc + (int)__popcll(am);
        }
        __syncthreads();
        acc = acc_s;
    }

    // ---- exact fallback (pathological only) ----------------------------
    if (acc < NOUT && cnt < valid) {
        unsigned* rvk = (unsigned*)skey;
        int*      ri  = (int*)sslot;
        while (acc < NOUT) {
            unsigned best = 0u;
            int bi = 0x7fffffff;
            for (int j = tid; j < A_TOT; j += NTH) {
                const unsigned k = K[j];
                if (k) {
                    int cat = (int)CT[j];
                    double bb[4];
                    decode_box(b, j, rg0, rg1, rg2, rg3, rg4, anchors, bb);
                    double shift = (double)cat * 1280.0;
                    double x1 = bb[0] + shift, y1 = bb[1] + shift;
                    double x2 = bb[2] + shift, y2 = bb[3] + shift;
                    double areaj = (x2 - x1) * (y2 - y1);
                    bool dead = false;
                    for (int r = 0; r < acc && !dead; ++r) {
                        int cd = aCT[r] - cat; if (cd < 0) cd = -cd;
                        if (cd <= 4) {
                            double ix1 = aX1[r] > x1 ? aX1[r] : x1;
                            double iy1 = aY1[r] > y1 ? aY1[r] : y1;
                            double ix2 = aX2[r] < x2 ? aX2[r] : x2;
                            double iy2 = aY2[r] < y2 ? aY2[r] : y2;
                            double iw = ix2 - ix1; if (iw < 0.0) iw = 0.0;
                            double ih = iy2 - iy1; if (ih < 0.0) ih = 0.0;
                            double inter = iw * ih;
                            double iou = inter / (aAR[r] + areaj - inter + 1e-9);
                            if (iou > 0.5) dead = true;
                        }
                    }
                    if (!dead && k > best) { best = k; bi = j; }  // j ascending: ties keep first index
                }
            }
            rvk[tid] = best; ri[tid] = bi;
            __syncthreads();
            for (int off = NTH / 2; off > 0; off >>= 1) {
                if (tid < off) {
                    if (rvk[tid + off] > rvk[tid] ||
                        (rvk[tid + off] == rvk[tid] && ri[tid + off] < ri[tid])) {
                        rvk[tid] = rvk[tid + off]; ri[tid] = ri[tid + off];
                    }
                }
                __syncthreads();
            }
            if (rvk[0] == 0u) break;
            if (tid == 0) {
                int j = ri[0];
                int cat = (int)CT[j];
                double bb[4];
                decode_box(b, j, rg0, rg1, rg2, rg3, rg4, anchors, bb);
                double shift = (double)cat * 1280.0;
                double x1 = bb[0] + shift, y1 = bb[1] + shift;
                double x2 = bb[2] + shift, y2 = bb[3] + shift;
                aX1[acc] = x1; aY1[acc] = y1; aX2[acc] = x2; aY2[acc] = y2;
                aAR[acc] = (x2 - x1) * (y2 - y1); aCT[acc] = cat;
                float* o = obuf + acc * 6;
                o[0] = (float)bb[0]; o[1] = (float)bb[1];
                o[2] = (float)bb[2]; o[3] = (float)bb[3];
                o[4] = (float)(1.0 / (1.0 + exp(-(double)__uint_as_float(rvk[0]))));
                o[5] = (float)cat;
                acc_s = acc + 1;
            }
            __syncthreads();
            acc = acc_s;
        }
    }
    __syncthreads();

    // ---- write output ---------------------------------------------------
    float* O = out + (size_t)b * NOUT * 6;
    for (int i = tid; i < NOUT * 6; i += NTH) O[i] = obuf[i];
}

extern "C" void kernel_launch(void* const* d_in, const int* in_sizes, int n_in,
                              void* d_out, int out_size, void* d_ws, size_t ws_size,
                              hipStream_t stream)
{
    // input dict order is interleaved: logits_i, regress_i pairs, anchors last
    const float* lg0 = (const float*)d_in[0];
    const float* rg0 = (const float*)d_in[1];
    const float* lg1 = (const float*)d_in[2];
    const float* rg1 = (const float*)d_in[3];
    const float* lg2 = (const float*)d_in[4];
    const float* rg2 = (const float*)d_in[5];
    const float* lg3 = (const float*)d_in[6];
    const float* rg3 = (const float*)d_in[7];
    const float* lg4 = (const float*)d_in[8];
    const float* rg4 = (const float*)d_in[9];
    const float* anchors = (const float*)d_in[10];

    char* ws = (char*)d_ws;
    unsigned*      keys   = (unsigned*)ws;                          // 2,455,296
    unsigned char* cats   = (unsigned char*)(ws + 2455296);         //   613,824
    unsigned*      hist   = (unsigned*)(ws + 3069184);              //   131,072
    int*           scount = (int*)(ws + 3200256);                   // 8 * 256 B = 2048 (contiguous after hist)
    unsigned long long* stage = (unsigned long long*)(ws + 3202560);// 8*8192*8 = 524,288
    double*        cbox   = (double*)(ws + 3726848);                // 8*1024*32 = 262,144
    float*         cscore = (float*)(ws + 3988992);                 // 8*1024*4  =  32,768

    hipMemsetAsync(hist, 0, 131072 + 2048, stream);

    prep_kernel<<<dim3(NCHUNKS, NANCH, NBATCH), 512, 0, stream>>>(
        lg0, lg1, lg2, lg3, lg4, keys, cats, hist, stage, scount);

    greedy_kernel<<<NBATCH, NTH, 0, stream>>>(
        keys, cats, rg0, rg1, rg2, rg3, rg4, anchors,
        hist, stage, scount, cbox, cscore, (float*)d_out);
}